// Round 24
// baseline (264.176 us; speedup 1.0000x reference)
//
#include <hip/hip_runtime.h>

// Sizes
#define TW 120
#define TB 2
#define TJ 24
#define TH 128
#define TNH 8
#define THD 16
#define TF 256
#define TD 216
#define TROWS (TW*TB*TJ)   // 5760
#define TEMB (TJ*TH)       // 3072
#define TBF 240
#define KPAD 256           // padded K for embed MFMA (2 chunks of 128)

#define QCH 60
#define LDT 136    // bf16 MFMA LDS row stride (shorts)
#define SPAD (TH + 4)
#define HSEG (TW*THD)      // 1920 floats per (b,j,head) segment

typedef float f4 __attribute__((ext_vector_type(4)));
typedef short bf8 __attribute__((ext_vector_type(8)));
typedef short s4 __attribute__((ext_vector_type(4)));

__device__ __forceinline__ short f2bf(float x) {
    union { float f; unsigned u; } v; v.f = x;
    unsigned r = (v.u + 0x7FFFu + ((v.u >> 16) & 1u)) >> 16;
    return (short)r;
}

// ---------------- weight conversion + gathers (fused) ----------------
#define NW_QKV_S 196608
#define NW_O_S    65536
#define NW_QKV_T 4718592
#define NW_O_T   1572864
#define NW_1      131072
#define NW_2      131072
#define OFF_O_S   (NW_QKV_S)
#define OFF_QKV_T (OFF_O_S + NW_O_S)
#define OFF_O_T   (OFF_QKV_T + NW_QKV_T)
#define OFF_W1    (OFF_O_T + NW_O_T)
#define OFF_W2    (OFF_W1 + NW_1)
#define NW_TOT    (OFF_W2 + NW_2)      // 6815744
#define NB_CONV   (NW_TOT / 4 / 256)   // 6656 exact
#define NB_WEMB   (TEMB * KPAD / 4 / 256)  // 768 exact
#define NB_CBUF   (TBF * KPAD / 4 / 256)   // 60 exact

__global__ void convgather_kernel(const float* __restrict__ Wqkv_s, const float* __restrict__ Wo_s,
                                  const float* __restrict__ Wqkv_t, const float* __restrict__ Wo_t,
                                  const float* __restrict__ W1, const float* __restrict__ W2,
                                  short* __restrict__ dst,
                                  const float* __restrict__ Wemb, short* __restrict__ wembbf,
                                  const float* __restrict__ src, const float* __restrict__ tgt,
                                  short* __restrict__ cbufbf) {
    int bx = blockIdx.x, tid = threadIdx.x;
    if (bx < NB_CONV) {
        size_t i = ((size_t)bx * 256 + tid) * 4;
        const float* s; size_t off;
        if (i < NW_QKV_S)       { s = Wqkv_s; off = i; }
        else if (i < OFF_QKV_T) { s = Wo_s;   off = i - OFF_O_S; }
        else if (i < OFF_O_T)   { s = Wqkv_t; off = i - OFF_QKV_T; }
        else if (i < OFF_W1)    { s = Wo_t;   off = i - OFF_O_T; }
        else if (i < OFF_W2)    { s = W1;     off = i - OFF_W1; }
        else                    { s = W2;     off = i - OFF_W2; }
        f4 v = *(const f4*)(s + off);
        s4 o = { f2bf(v[0]), f2bf(v[1]), f2bf(v[2]), f2bf(v[3]) };
        *(s4*)(dst + i) = o;
    } else if (bx < NB_CONV + NB_WEMB) {
        int g = (bx - NB_CONV) * 256 + tid;     // f4 group in [3072][256]
        int row = g >> 6;
        int colg = (g & 63) * 4;
        s4 o = {0, 0, 0, 0};
        if (colg < TD) {                         // colg<=212 -> 4 elems in range
            f4 v = *(const f4*)(Wemb + (size_t)row * TD + colg);
            o = { f2bf(v[0]), f2bf(v[1]), f2bf(v[2]), f2bf(v[3]) };
        }
        *(s4*)(wembbf + (size_t)row * KPAD + colg) = o;
    } else {
        int g = (bx - NB_CONV - NB_WEMB) * 256 + tid;  // f4 group in [240][256]
        int row = g >> 6;
        int colg = (g & 63) * 4;
        int b = row & 1, t = row >> 1;
        s4 o = {0, 0, 0, 0};
        if (colg < TD) {
            const float* sp = (t < 60) ? (src + ((size_t)b * 60 + t) * TD)
                                       : (tgt + ((size_t)b * 61 + (t - 60)) * TD);
            f4 v = *(const f4*)(sp + colg);
            o = { f2bf(v[0]), f2bf(v[1]), f2bf(v[2]), f2bf(v[3]) };
        }
        *(s4*)(cbufbf + (size_t)row * KPAD + colg) = o;
    }
}

// ---------------- MFMA building blocks ----------------
__device__ __forceinline__ void stage_bf(short* Ds, const short* __restrict__ src,
                                         size_t rstride, int nrows, int tid) {
    int r = tid >> 2, s = (tid & 3) * 32;
    short* d = Ds + r * LDT + s;
    if (r < nrows) {
        const short* p = src + (size_t)r * rstride + s;
        *(bf8*)(d)      = *(const bf8*)(p);
        *(bf8*)(d + 8)  = *(const bf8*)(p + 8);
        *(bf8*)(d + 16) = *(const bf8*)(p + 16);
        *(bf8*)(d + 24) = *(const bf8*)(p + 24);
    } else {
        bf8 z = {0,0,0,0,0,0,0,0};
        *(bf8*)(d) = z; *(bf8*)(d+8) = z; *(bf8*)(d+16) = z; *(bf8*)(d+24) = z;
    }
}

__device__ __forceinline__ void mfma_tile64(const short* As, const short* Bs,
                                            int wave, int lane, f4 acc[2][2]) {
    int wm = wave >> 1, wn = wave & 1;
    int lrow = lane & 15, lk = (lane >> 4) * 8;
    #pragma unroll
    for (int ks = 0; ks < 4; ++ks) {
        bf8 a0 = *(const bf8*)&As[(wm*32      + lrow) * LDT + ks*32 + lk];
        bf8 a1 = *(const bf8*)&As[(wm*32 + 16 + lrow) * LDT + ks*32 + lk];
        bf8 b0 = *(const bf8*)&Bs[(wn*32      + lrow) * LDT + ks*32 + lk];
        bf8 b1 = *(const bf8*)&Bs[(wn*32 + 16 + lrow) * LDT + ks*32 + lk];
        acc[0][0] = __builtin_amdgcn_mfma_f32_16x16x32_bf16(a0, b0, acc[0][0], 0, 0, 0);
        acc[0][1] = __builtin_amdgcn_mfma_f32_16x16x32_bf16(a0, b1, acc[0][1], 0, 0, 0);
        acc[1][0] = __builtin_amdgcn_mfma_f32_16x16x32_bf16(a1, b0, acc[1][0], 0, 0, 0);
        acc[1][1] = __builtin_amdgcn_mfma_f32_16x16x32_bf16(a1, b1, acc[1][1], 0, 0, 0);
    }
}

// ---------------- embedding MFMA GEMM + bias + PE ----------------
// grid (4, 48): M=240, N=3072, K=256 (zero-padded from 216), 2 chunks of 128.
__global__ __launch_bounds__(256) void mfma_embed_kernel(
        const short* __restrict__ cbufbf, const short* __restrict__ wembbf,
        const float* __restrict__ bemb, float* __restrict__ x0,
        short* __restrict__ x0bf, float* __restrict__ r0,
        short* __restrict__ r0bf) {
    __shared__ short As[64 * LDT], Bs[64 * LDT];
    int tid = threadIdx.x;
    int m0 = blockIdx.x * 64, n0 = blockIdx.y * 64;
    int mrem = TBF - m0; if (mrem > 64) mrem = 64;
    int wave = tid >> 6, lane = tid & 63;
    f4 acc[2][2] = {{{0,0,0,0},{0,0,0,0}},{{0,0,0,0},{0,0,0,0}}};
    #pragma unroll
    for (int kk = 0; kk < 2; ++kk) {
        stage_bf(As, cbufbf + (size_t)m0 * KPAD + kk * 128, KPAD, mrem, tid);
        stage_bf(Bs, wembbf + (size_t)n0 * KPAD + kk * 128, KPAD, 64, tid);
        __syncthreads();
        mfma_tile64(As, Bs, wave, lane, acc);
        __syncthreads();
    }
    int wm = wave >> 1, wn = wave & 1, lrow = lane & 15, gr = (lane >> 4) * 4;
    #pragma unroll
    for (int ni = 0; ni < 2; ++ni) {
        int col = n0 + wn*32 + ni*16 + lrow;
        float bv = bemb[col];
        float freq = expf((float)(col & ~1) * (-9.2103403719761836f / 3072.0f));
        float peodd = (col & 1) ? 1.f : 0.f;
        #pragma unroll
        for (int mi = 0; mi < 2; ++mi)
            #pragma unroll
            for (int rg = 0; rg < 4; ++rg) {
                int tr = wm*32 + mi*16 + gr + rg;
                if (tr < mrem) {
                    int grow = m0 + tr;
                    int t = grow >> 1;
                    float ang = (float)t * freq;
                    float pe = peodd ? cosf(ang) : sinf(ang);
                    float v = acc[mi][ni][rg] + bv + pe;
                    size_t off = (size_t)grow * TEMB + col;
                    x0[off] = v;
                    r0[off] = v;
                    short bvs = f2bf(v);
                    x0bf[off] = bvs;
                    r0bf[off] = bvs;
                }
            }
    }
}

// ---------------- mega QKV ----------------
// Temporal outputs head-major: [(b*TJ+j)*TNH+head][t][d]. Spatial frame-major.
__global__ __launch_bounds__(256) void mfma_qkvmega_kernel(
        const short* __restrict__ A2, const short* __restrict__ A3,
        const short* __restrict__ Wt, const short* __restrict__ Ws,
        const float* __restrict__ bt, const float* __restrict__ bs,
        float* __restrict__ Qp2, float* __restrict__ Kb2, float* __restrict__ Vb2,
        float* __restrict__ Qs_, float* __restrict__ Ks_, float* __restrict__ Vs_,
        float* __restrict__ Qt_, float* __restrict__ Kt_, float* __restrict__ Vt_,
        int p2n, int n0base) {
    __shared__ short As[64 * LDT], Bs[64 * LDT];
    int tid = threadIdx.x;
    int m0 = blockIdx.x * 64, j = blockIdx.z, yy = blockIdx.y;
    int mrem = TBF - m0; if (mrem > 64) mrem = 64;
    const short* Abf; const short* Wbf; const float* bias; int bofs, n0;
    float *dq, *dk, *dv;
    int headmajor;
    if (yy < p2n) {
        n0 = n0base + yy * 64;
        Abf = A2;
        Wbf = Wt + (size_t)j * 3 * TH * TH + (size_t)n0 * TH;
        bias = bt; bofs = j * 3 * TH;
        dq = Qp2; dk = Kb2; dv = Vb2;
        headmajor = 1;
    } else {
        int y2 = yy - p2n;
        int tmp = (y2 >= 6);
        n0 = (tmp ? y2 - 6 : y2) * 64;
        Abf = A3;
        if (tmp) { Wbf = Wt + (size_t)j * 3 * TH * TH + (size_t)n0 * TH; bias = bt; bofs = j * 3 * TH;
                   dq = Qt_; dk = Kt_; dv = Vt_; headmajor = 1; }
        else     { Wbf = Ws + (size_t)n0 * TH; bias = bs; bofs = 0;
                   dq = Qs_; dk = Ks_; dv = Vs_; headmajor = 0; }
    }
    stage_bf(As, Abf + (size_t)m0 * TEMB + j * TH, TEMB, mrem, tid);
    stage_bf(Bs, Wbf, TH, 64, tid);
    __syncthreads();
    int wave = tid >> 6, lane = tid & 63;
    f4 acc[2][2] = {{{0,0,0,0},{0,0,0,0}},{{0,0,0,0},{0,0,0,0}}};
    mfma_tile64(As, Bs, wave, lane, acc);
    int wm = wave >> 1, wn = wave & 1, lrow = lane & 15, gr = (lane >> 4) * 4;
    float* dst = (n0 < TH) ? dq : ((n0 < 2 * TH) ? dk : dv);
    int cb = n0 & (TH - 1);
    #pragma unroll
    for (int ni = 0; ni < 2; ++ni) {
        float bv = bias[bofs + n0 + wn*32 + ni*16 + lrow];
        int col = cb + wn*32 + ni*16 + lrow;
        #pragma unroll
        for (int mi = 0; mi < 2; ++mi)
            #pragma unroll
            for (int rg = 0; rg < 4; ++rg) {
                int tr = wm*32 + mi*16 + gr + rg;
                if (tr < mrem) {
                    int row = m0 + tr;
                    float v = acc[mi][ni][rg] + bv;
                    if (headmajor) {
                        int bb = row & 1, tt = row >> 1;
                        int hd = col >> 4, dd = col & 15;
                        dst[((size_t)((bb * TJ + j) * TNH + hd) * TW + tt) * THD + dd] = v;
                    } else {
                        dst[(size_t)(row * TJ + j) * TH + col] = v;
                    }
                }
            }
    }
}

// ---------------- mega attention: spatial (240) + temporal (384) -------------
// Temporal: block = (b,j,head); lane = QUERY; loop over keys with wave-uniform
// broadcast LDS reads of baseline K/V. No cross-lane ops at all.
__global__ __launch_bounds__(256) void attn_mega_kernel(
        const float* __restrict__ Qc_g, const float* __restrict__ Kc_g, const float* __restrict__ Vc_g,
        const float* __restrict__ Qs_g, const float* __restrict__ Ks_g, const float* __restrict__ Vs_g,
        const float* __restrict__ Qt_g, const float* __restrict__ Kt_g, const float* __restrict__ Vt_g,
        short* __restrict__ Oc, short* __restrict__ Os, short* __restrict__ Ot,
        int docausal) {
    __shared__ __align__(16) float smem[3 * TJ * SPAD];
    int bx = blockIdx.x;
    int tid = threadIdx.x;

    if (bx < 240) {
        // ---- spatial (frame-major inputs), 256 threads ----
        float* Qs = smem;
        float* Ks = smem + TJ * SPAD;
        float* Vs = smem + 2 * TJ * SPAD;
        int b = bx & 1, t = bx >> 1;
        int base = (t * TB + b) * TJ;
        for (int i = tid; i < TJ * 32; i += 256) {
            int rr = i >> 5, c4 = i & 31;
            ((f4*)(Qs + rr * SPAD))[c4] = ((const f4*)(Qs_g + (size_t)(base + rr) * TH))[c4];
            ((f4*)(Ks + rr * SPAD))[c4] = ((const f4*)(Ks_g + (size_t)(base + rr) * TH))[c4];
            ((f4*)(Vs + rr * SPAD))[c4] = ((const f4*)(Vs_g + (size_t)(base + rr) * TH))[c4];
        }
        __syncthreads();
        if (tid >= 192) return;
        int qj = tid % TJ;
        int head = tid / TJ;
        int hb = head * THD;
        float qv[THD];
        #pragma unroll
        for (int u = 0; u < THD; ++u) qv[u] = Qs[qj * SPAD + hb + u];
        float sc[TJ];
        float m = -1e30f;
        #pragma unroll
        for (int k = 0; k < TJ; ++k) {
            float a = 0.f;
            #pragma unroll
            for (int u = 0; u < THD; ++u) a += qv[u] * Ks[k * SPAD + hb + u];
            sc[k] = a * 0.25f;
            m = fmaxf(m, sc[k]);
        }
        float sum = 0.f;
        #pragma unroll
        for (int k = 0; k < TJ; ++k) { sc[k] = __expf(sc[k] - m); sum += sc[k]; }
        float inv = 1.0f / sum;
        float o[THD];
        #pragma unroll
        for (int u = 0; u < THD; ++u) o[u] = 0.f;
        #pragma unroll
        for (int k = 0; k < TJ; ++k) {
            #pragma unroll
            for (int u = 0; u < THD; ++u) o[u] += sc[k] * Vs[k * SPAD + hb + u];
        }
        size_t off = (size_t)(base + qj) * TH + hb;
        #pragma unroll
        for (int u = 0; u < THD; ++u) Os[off + u] = f2bf(o[u] * inv);
        return;
    }

    // ---- temporal: block = (b,j,head) ----
    int cx = bx - 240;                    // 0..383
    int head = cx & 7;
    int j = (cx >> 3) % TJ;
    int b = (cx >> 3) / TJ;
    size_t base = (size_t)((b * TJ + j) * TNH + head) * HSEG;
    float* Kb = smem;                     // 120*16 = 1920
    float* Vb = smem + 1920;              // 1920
    for (int i = tid; i < 480; i += 256) {
        ((f4*)Kb)[i] = ((const f4*)(Kc_g + base))[i];
        ((f4*)Vb)[i] = ((const f4*)(Vc_g + base))[i];
    }
    __syncthreads();
    int wave = tid >> 6, lane = tid & 63;
    int iscausal = (wave < 2);
    if (iscausal && !docausal) return;
    int qbase = (wave & 1) * 60;
    int act = (lane < 60);
    int q = qbase + (act ? lane : 59);
    const float* Qg = iscausal ? Qc_g : Qt_g;
    f4 Qr0 = *(const f4*)(Qg + base + (size_t)q * THD);
    f4 Qr1 = *(const f4*)(Qg + base + (size_t)q * THD + 4);
    f4 Qr2 = *(const f4*)(Qg + base + (size_t)q * THD + 8);
    f4 Qr3 = *(const f4*)(Qg + base + (size_t)q * THD + 12);
    f4 Ks0, Ks1, Ks2, Ks3, Vs0, Vs1, Vs2, Vs3;
    if (!iscausal) {
        Ks0 = *(const f4*)(Kt_g + base + (size_t)q * THD);
        Ks1 = *(const f4*)(Kt_g + base + (size_t)q * THD + 4);
        Ks2 = *(const f4*)(Kt_g + base + (size_t)q * THD + 8);
        Ks3 = *(const f4*)(Kt_g + base + (size_t)q * THD + 12);
        Vs0 = *(const f4*)(Vt_g + base + (size_t)q * THD);
        Vs1 = *(const f4*)(Vt_g + base + (size_t)q * THD + 4);
        Vs2 = *(const f4*)(Vt_g + base + (size_t)q * THD + 8);
        Vs3 = *(const f4*)(Vt_g + base + (size_t)q * THD + 12);
    }
    f4 a0 = {0,0,0,0}, a1 = {0,0,0,0}, a2 = {0,0,0,0}, a3 = {0,0,0,0};
    float sum = 0.f;
    int qc = iscausal ? q : (q - 1);      // last valid baseline key
    int klim = qbase + 60;                // 60 or 120, divisible by 4
    #pragma unroll 4
    for (int k = 0; k < klim; ++k) {
        const float* kr = Kb + k * 16;
        f4 d = Qr0 * ((const f4*)kr)[0] + Qr1 * ((const f4*)kr)[1]
             + Qr2 * ((const f4*)kr)[2] + Qr3 * ((const f4*)kr)[3];
        float s = (d[0] + d[1] + d[2] + d[3]) * 0.25f;
        float p = (k <= qc) ? __expf(s) : 0.f;
        sum += p;
        const float* vr = Vb + k * 16;
        a0 += p * ((const f4*)vr)[0];
        a1 += p * ((const f4*)vr)[1];
        a2 += p * ((const f4*)vr)[2];
        a3 += p * ((const f4*)vr)[3];
    }
    if (!iscausal) {  // diagonal from lane-private special K/V
        f4 d = Qr0 * Ks0 + Qr1 * Ks1 + Qr2 * Ks2 + Qr3 * Ks3;
        float p = __expf((d[0] + d[1] + d[2] + d[3]) * 0.25f);
        sum += p;
        a0 += p * Vs0; a1 += p * Vs1; a2 += p * Vs2; a3 += p * Vs3;
    }
    if (act) {
        float inv = 1.0f / sum;
        short* O = iscausal ? Oc : Ot;
        size_t off = (size_t)((q * TB + b) * TJ + j) * TH + head * THD;
        s4 o0 = { f2bf(a0[0]*inv), f2bf(a0[1]*inv), f2bf(a0[2]*inv), f2bf(a0[3]*inv) };
        s4 o1 = { f2bf(a1[0]*inv), f2bf(a1[1]*inv), f2bf(a1[2]*inv), f2bf(a1[3]*inv) };
        s4 o2 = { f2bf(a2[0]*inv), f2bf(a2[1]*inv), f2bf(a2[2]*inv), f2bf(a2[3]*inv) };
        s4 o3 = { f2bf(a3[0]*inv), f2bf(a3[1]*inv), f2bf(a3[2]*inv), f2bf(a3[3]*inv) };
        *(s4*)(O + off)      = o0;
        *(s4*)(O + off + 4)  = o1;
        *(s4*)(O + off + 8)  = o2;
        *(s4*)(O + off + 12) = o3;
    }
}

// ---------------- OLN compute core ----------------
__device__ __forceinline__ void oln_compute(
        const short* __restrict__ Abf, const short* __restrict__ Wbf,
        const float* __restrict__ bias, const float* __restrict__ resid,
        const float* __restrict__ g, const float* __restrict__ bln,
        int perJoint, int m0, int j,
        short* As, short* Bs, float* rsum, float* rsq, float* lnm, float* lnr,
        float o0[4], float o1[4]) {
    int tid = threadIdx.x;
    { int r = tid >> 4, s = (tid & 15) * 8;
      *(bf8*)&As[r * LDT + s] = *(const bf8*)(Abf + (size_t)(m0 + r) * TEMB + j * TH + s); }
    { int r = tid >> 1, s = (tid & 1) * 64;
      const short* p = Wbf + (perJoint ? (size_t)j * TH * TH : 0) + (size_t)r * TH + s;
      short* d = &Bs[r * LDT + s];
      #pragma unroll
      for (int cc = 0; cc < 64; cc += 8) *(bf8*)(d + cc) = *(const bf8*)(p + cc); }
    __syncthreads();
    int wave = tid >> 6, lane = tid & 63, lrow = lane & 15, lk = (lane >> 4) * 8, gr = (lane >> 4) * 4;
    f4 acc[2] = {{0,0,0,0},{0,0,0,0}};
    #pragma unroll
    for (int ks = 0; ks < 4; ++ks) {
        bf8 a  = *(const bf8*)&As[lrow * LDT + ks*32 + lk];
        bf8 b0 = *(const bf8*)&Bs[(wave*32      + lrow) * LDT + ks*32 + lk];
        bf8 b1 = *(const bf8*)&Bs[(wave*32 + 16 + lrow) * LDT + ks*32 + lk];
        acc[0] = __builtin_amdgcn_mfma_f32_16x16x32_bf16(a, b0, acc[0], 0, 0, 0);
        acc[1] = __builtin_amdgcn_mfma_f32_16x16x32_bf16(a, b1, acc[1], 0, 0, 0);
    }
    int col0 = wave*32 + lrow, col1 = col0 + 16;
    int bofs = perJoint ? j * TH : 0;
    float bv0 = bias[bofs + col0], bv1 = bias[bofs + col1];
    float v0[4], v1[4], sr_[4], sq_[4];
    #pragma unroll
    for (int rg = 0; rg < 4; ++rg) {
        size_t ro = (size_t)(m0 + gr + rg) * TEMB + j * TH;
        v0[rg] = acc[0][rg] + bv0 + resid[ro + col0];
        v1[rg] = acc[1][rg] + bv1 + resid[ro + col1];
        sr_[rg] = v0[rg] + v1[rg];
        sq_[rg] = v0[rg]*v0[rg] + v1[rg]*v1[rg];
    }
    #pragma unroll
    for (int o = 1; o < 16; o <<= 1) {
        #pragma unroll
        for (int rg = 0; rg < 4; ++rg) { sr_[rg] += __shfl_xor(sr_[rg], o); sq_[rg] += __shfl_xor(sq_[rg], o); }
    }
    if (lrow == 0) {
        #pragma unroll
        for (int rg = 0; rg < 4; ++rg) { rsum[wave*16 + gr + rg] = sr_[rg]; rsq[wave*16 + gr + rg] = sq_[rg]; }
    }
    __syncthreads();
    if (tid < 16) {
        float s = rsum[tid] + rsum[16 + tid] + rsum[32 + tid] + rsum[48 + tid];
        float q = rsq[tid] + rsq[16 + tid] + rsq[32 + tid] + rsq[48 + tid];
        float mean = s * (1.0f / TH);
        float var = q * (1.0f / TH) - mean * mean;
        lnm[tid] = mean; lnr[tid] = rsqrtf(var + 1e-5f);
    }
    __syncthreads();
    float g0 = g[col0], g1 = g[col1], l0 = bln[col0], l1 = bln[col1];
    #pragma unroll
    for (int rg = 0; rg < 4; ++rg) {
        int row = gr + rg;
        float mean = lnm[row], rs = lnr[row];
        o0[rg] = (v0[rg] - mean) * rs * g0 + l0;
        o1[rg] = (v1[rg] - mean) * rs * g1 + l1;
    }
}

// fused OLN: part2-temporal (np2 blocks) + part3 spatial+temporal (360 blocks)
__global__ __launch_bounds__(256) void mfma_olnfused_kernel(
        const short* __restrict__ A2, const short* __restrict__ Wt,
        const float* __restrict__ bt, const float* __restrict__ res2,
        const float* __restrict__ tg, const float* __restrict__ tl,
        short* __restrict__ Yb2,
        const short* __restrict__ A3s, const short* __restrict__ Ws,
        const float* __restrict__ bs, const short* __restrict__ A3t,
        const float* __restrict__ res3,
        const float* __restrict__ sg, const float* __restrict__ sl,
        short* __restrict__ Yb3, int np2) {
    __shared__ short As[16 * LDT];
    __shared__ short Bs[128 * LDT];
    __shared__ float rsum[64], rsq[64], lnm[16], lnr[16];
    int bx = blockIdx.x;
    int tid = threadIdx.x;
    int wave = tid >> 6, lane = tid & 63, lrow = lane & 15, gr = (lane >> 4) * 4;
    int col0 = wave*32 + lrow, col1 = col0 + 16;
    if (bx < np2) {
        int m0 = (bx % 15) * 16, j = bx / 15;
        float o0[4], o1[4];
        oln_compute(A2, Wt, bt, res2, tg, tl, 1, m0, j,
                    As, Bs, rsum, rsq, lnm, lnr, o0, o1);
        #pragma unroll
        for (int rg = 0; rg < 4; ++rg) {
            size_t ro = (size_t)(m0 + gr + rg) * TEMB + j * TH;
            Yb2[ro + col0] = f2bf(o0[rg]);
            Yb2[ro + col1] = f2bf(o1[rg]);
        }
    } else {
        int idx = bx - np2;
        int m0 = (idx % 15) * 16, j = idx / 15;
        float s0[4], s1[4], t0[4], t1[4];
        oln_compute(A3s, Ws, bs, res3, sg, sl, 0, m0, j,
                    As, Bs, rsum, rsq, lnm, lnr, s0, s1);
        __syncthreads();
        oln_compute(A3t, Wt, bt, res3, tg, tl, 1, m0, j,
                    As, Bs, rsum, rsq, lnm, lnr, t0, t1);
        #pragma unroll
        for (int rg = 0; rg < 4; ++rg) {
            size_t ro = (size_t)(m0 + gr + rg) * TEMB + j * TH;
            Yb3[ro + col0] = f2bf(t0[rg] + s0[rg]);
            Yb3[ro + col1] = f2bf(t1[rg] + s1[rg]);
        }
    }
}

// ---------------- fused FFN (ffn1 + ffn2, F kept in LDS) ----------------
// Per block: 64 rows. ffn1: Y(64x128) x W1^T -> F(64x256) relu*2 in LDS
// (two 128-col halves, Fs reused); ffn2: F x W2^T -> 64x128, accumulated
// across halves in registers. Bit-exact same accumulation order as the
// previous separate ffn1/ffn2 kernels.
__global__ __launch_bounds__(256) void mfma_ffnf_kernel(
        const short* __restrict__ Ybf, const short* __restrict__ W1bf,
        const float* __restrict__ b1, const short* __restrict__ W2bf,
        const float* __restrict__ b2, float* __restrict__ OutAf,
        short* __restrict__ OutAbf, float* __restrict__ OutBf,
        short* __restrict__ OutBbf, int splitrow) {
    __shared__ short As[64 * LDT], Bs[64 * LDT], Fs[64 * LDT];
    int tid = threadIdx.x;
    int m0 = blockIdx.x * 64;
    int wave = tid >> 6, lane = tid & 63;
    int wm = wave >> 1, wn = wave & 1, lrow = lane & 15, gr = (lane >> 4) * 4;
    stage_bf(As, Ybf + (size_t)m0 * TH, TH, 64, tid);
    f4 acc2[2][2][2] = {};
    #pragma unroll
    for (int half = 0; half < 2; ++half) {
        // ffn1: F cols half*128 .. half*128+127 -> Fs
        #pragma unroll
        for (int sub = 0; sub < 2; ++sub) {
            int nt = half * 2 + sub;
            stage_bf(Bs, W1bf + (size_t)(nt * 64) * TH, TH, 64, tid);
            __syncthreads();
            f4 acc[2][2] = {{{0,0,0,0},{0,0,0,0}},{{0,0,0,0},{0,0,0,0}}};
            mfma_tile64(As, Bs, wave, lane, acc);
            #pragma unroll
            for (int ni = 0; ni < 2; ++ni) {
                int colloc = wn*32 + ni*16 + lrow;
                float bv = b1[nt*64 + colloc];
                #pragma unroll
                for (int mi = 0; mi < 2; ++mi)
                    #pragma unroll
                    for (int rg = 0; rg < 4; ++rg) {
                        int tr = wm*32 + mi*16 + gr + rg;
                        float v = 2.0f * fmaxf(acc[mi][ni][rg] + bv, 0.0f);
                        Fs[tr * LDT + sub*64 + colloc] = f2bf(v);
                    }
            }
            __syncthreads();
        }
        // ffn2 partial for this K-chunk (both output n-tiles)
        #pragma unroll
        for (int nt2 = 0; nt2 < 2; ++nt2) {
            stage_bf(Bs, W2bf + (size_t)(nt2 * 64) * TF + half * 128, TF, 64, tid);
            __syncthreads();
            mfma_tile64(Fs, Bs, wave, lane, acc2[nt2]);
            __syncthreads();
        }
    }
    #pragma unroll
    for (int nt2 = 0; nt2 < 2; ++nt2)
        #pragma unroll
        for (int ni = 0; ni < 2; ++ni) {
            int col = nt2*64 + wn*32 + ni*16 + lrow;
            float bv = b2[col];
            #pragma unroll
            for (int mi = 0; mi < 2; ++mi)
                #pragma unroll
                for (int rg = 0; rg < 4; ++rg) {
                    int tr = wm*32 + mi*16 + gr + rg;
                    int row = m0 + tr;
                    float v = acc2[nt2][mi][ni][rg] + bv;
                    if (row < splitrow) {
                        size_t off = (size_t)row * TH + col;
                        OutAf[off] = v; OutAbf[off] = f2bf(v);
                    } else {
                        size_t off = (size_t)(row - splitrow) * TH + col;
                        OutBf[off] = v; OutBbf[off] = f2bf(v);
                    }
                }
        }
}

// ---------------- final projection + residual ----------------
__global__ void final_kernel(const float* __restrict__ r4, const float* __restrict__ Wout,
                             const float* __restrict__ bout, const float* __restrict__ src,
                             const float* __restrict__ tgt, float* __restrict__ out) {
    int idx = blockIdx.x * 256 + threadIdx.x;
    if (idx >= TB * TW * TD) return;
    int d = idx % TD;
    int t = (idx / TD) % TW;
    int b = idx / (TD * TW);
    int j = d / 9, o = d % 9;
    const float* rr = r4 + (size_t)((t * TB + b) * TJ + j) * TH;
    const float* wt = Wout + (size_t)o * TH;
    float acc = bout[o];
    #pragma unroll 4
    for (int h = 0; h < TH; ++h) acc += rr[h] * wt[h];
    float cv = (t < 60) ? src[((size_t)b * 60 + t) * TD + d]
                        : tgt[((size_t)b * 61 + (t - 60)) * TD + d];
    out[idx] = acc + cv;
}

extern "C" void kernel_launch(void* const* d_in, const int* in_sizes, int n_in,
                              void* d_out, int out_size, void* d_ws, size_t ws_size,
                              hipStream_t stream) {
    const float* src    = (const float*)d_in[0];
    const float* tgt    = (const float*)d_in[1];
    const float* Wemb   = (const float*)d_in[2];
    const float* bemb   = (const float*)d_in[3];
    const float* Wqkv_s = (const float*)d_in[4];
    const float* bqkv_s = (const float*)d_in[5];
    const float* Wo_s   = (const float*)d_in[6];
    const float* bo_s   = (const float*)d_in[7];
    const float* sn_g   = (const float*)d_in[8];
    const float* sn_b   = (const float*)d_in[9];
    const float* Wqkv_t = (const float*)d_in[10];
    const float* bqkv_t = (const float*)d_in[11];
    const float* Wo_t   = (const float*)d_in[12];
    const float* bo_t   = (const float*)d_in[13];
    const float* tn_g   = (const float*)d_in[14];
    const float* tn_b   = (const float*)d_in[15];
    const float* W1     = (const float*)d_in[16];
    const float* b1     = (const float*)d_in[17];
    const float* W2     = (const float*)d_in[18];
    const float* b2     = (const float*)d_in[19];
    const float* Wout   = (const float*)d_in[20];
    const float* bout   = (const float*)d_in[21];
    float* out = (float*)d_out;

    const size_t RH = (size_t)TROWS * TH;   // 737280
    float* f = (float*)d_ws;
    float* x0    = f;
    float* Kbase = x0 + RH;              // 4*RH (head-major per layer)
    float* Vbase = Kbase + 4 * RH;       // 4*RH
    float* r     = Vbase + 4 * RH;
    float* Qp2   = r + RH;
    float* Qs    = Qp2 + RH;
    float* Ks    = Qs + RH;
    float* Vs    = Ks + RH;
    float* Qt    = Vs + RH;
    float* Kt    = Qt + RH;
    float* Vt    = Kt + RH;
    float* Bb0   = Vt + RH;
    float* Bb1   = Bb0 + RH;
    short* sbase   = (short*)(Bb1 + RH);
    short* x0bf    = sbase;
    short* rbf     = x0bf + RH;
    short* attnb_c = rbf + RH;
    short* attnb_s = attnb_c + RH;
    short* attnb_t = attnb_s + RH;
    short* yball   = attnb_t + RH;       // 2*RH (part2 lower, part3 upper)
    short* fball   = yball + 2 * RH;     // 2*TROWS*TF (unused after FFN fusion)
    short* Bb0bf   = fball + 2 * (size_t)TROWS * TF;
    short* Bb1bf   = Bb0bf + RH;
    short* wbf     = Bb1bf + RH;         // NW_TOT shorts
    short* wembbf  = wbf + NW_TOT;       // TEMB*KPAD shorts
    short* cbufbf  = wembbf + (size_t)TEMB * KPAD;  // TBF*KPAD shorts

    const short* wqkvs_bf = wbf;
    const short* wos_bf   = wbf + OFF_O_S;
    const short* wqkvt_bf = wbf + OFF_QKV_T;
    const short* wot_bf   = wbf + OFF_O_T;
    const short* w1bf     = wbf + OFF_W1;
    const short* w2bf     = wbf + OFF_W2;

    // 0. weights -> bf16 (incl. padded Wemb) + gather concat -> padded bf16
    convgather_kernel<<<NB_CONV + NB_WEMB + NB_CBUF, 256, 0, stream>>>(
        Wqkv_s, Wo_s, Wqkv_t, Wo_t, W1, W2, wbf,
        Wemb, wembbf, src, tgt, cbufbf);

    // 1. embedding MFMA GEMM (+bias+PE); writes x0/x0bf and r/rbf
    mfma_embed_kernel<<<dim3(4, 48), 256, 0, stream>>>(
        cbufbf, wembbf, bemb, x0, x0bf, r, rbf);

    // 2+3. per-layer mega launches
    const float* Binf = x0;
    const short* Binbf = x0bf;
    for (int l = 0; l < 4; ++l) {
        int p2n = (l < 3) ? 6 : 4;
        int n0base = (l < 3) ? 0 : 128;
        int np2 = (l < 3) ? 360 : 0;
        const short* wt_l = wqkvt_bf + (size_t)l * TJ * 3 * TH * TH;
        const short* ws_l = wqkvs_bf + (size_t)l * 3 * TH * TH;
        const float* bt_l = bqkv_t + (size_t)l * TJ * 3 * TH;
        const float* bs_l = bqkv_s + (size_t)l * 3 * TH;

        mfma_qkvmega_kernel<<<dim3(4, p2n + 12, 24), 256, 0, stream>>>(
            Binbf, rbf, wt_l, ws_l, bt_l, bs_l,
            Qp2, Kbase + l * RH, Vbase + l * RH,
            Qs, Ks, Vs, Qt, Kt, Vt, p2n, n0base);

        attn_mega_kernel<<<240 + 384, 256, 0, stream>>>(
            Qp2, Kbase + l * RH, Vbase + l * RH,
            Qs, Ks, Vs, Qt, Kt, Vt,
            attnb_c, attnb_s, attnb_t, (l < 3) ? 1 : 0);

        mfma_olnfused_kernel<<<np2 + 360, 256, 0, stream>>>(
            attnb_c, wot_bf + (size_t)l * TJ * TH * TH, bo_t + (size_t)l * TJ * TH,
            Binf, tn_g + l * TH, tn_b + l * TH, yball,
            attnb_s, wos_bf + (size_t)l * TH * TH, bo_s + (size_t)l * TH,
            attnb_t, r, sn_g + l * TH, sn_b + l * TH, yball + RH, np2);

        if (l < 3) {
            float* Boutf = (l & 1) ? Bb1 : Bb0;
            short* Boutbf = (l & 1) ? Bb1bf : Bb0bf;
            mfma_ffnf_kernel<<<180, 256, 0, stream>>>(
                yball, w1bf + (size_t)l * TF * TH, b1 + l * TF,
                w2bf + (size_t)l * TH * TF, b2 + l * TH,
                Boutf, Boutbf, r, rbf, TROWS);
            Binf = Boutf; Binbf = Boutbf;
        } else {
            mfma_ffnf_kernel<<<90, 256, 0, stream>>>(
                yball + RH, w1bf + (size_t)l * TF * TH, b1 + l * TF,
                w2bf + (size_t)l * TH * TF, b2 + l * TH,
                r, rbf, r, rbf, 0);
        }
    }

    // 4. output projection + residual
    final_kernel<<<(TB * TW * TD + 255) / 256, 256, 0, stream>>>(r, Wout, bout, src, tgt, out);
}

// Round 25
// 250.371 us; speedup vs baseline: 1.0551x; 1.0551x over previous
//
#include <hip/hip_runtime.h>

// Sizes
#define TW 120
#define TB 2
#define TJ 24
#define TH 128
#define TNH 8
#define THD 16
#define TF 256
#define TD 216
#define TROWS (TW*TB*TJ)   // 5760
#define TEMB (TJ*TH)       // 3072
#define TBF 240
#define KPAD 256           // padded K for embed MFMA (2 chunks of 128)

#define QCH 60
#define LDT 136    // bf16 MFMA LDS row stride (shorts)
#define SPAD (TH + 4)
#define HSEG (TW*THD)      // 1920 floats per (b,j,head) segment

typedef float f4 __attribute__((ext_vector_type(4)));
typedef short bf8 __attribute__((ext_vector_type(8)));
typedef short s4 __attribute__((ext_vector_type(4)));

__device__ __forceinline__ short f2bf(float x) {
    union { float f; unsigned u; } v; v.f = x;
    unsigned r = (v.u + 0x7FFFu + ((v.u >> 16) & 1u)) >> 16;
    return (short)r;
}

// ---------------- weight conversion + gathers (fused) ----------------
#define NW_QKV_S 196608
#define NW_O_S    65536
#define NW_QKV_T 4718592
#define NW_O_T   1572864
#define NW_1      131072
#define NW_2      131072
#define OFF_O_S   (NW_QKV_S)
#define OFF_QKV_T (OFF_O_S + NW_O_S)
#define OFF_O_T   (OFF_QKV_T + NW_QKV_T)
#define OFF_W1    (OFF_O_T + NW_O_T)
#define OFF_W2    (OFF_W1 + NW_1)
#define NW_TOT    (OFF_W2 + NW_2)      // 6815744
#define NB_CONV   (NW_TOT / 4 / 256)   // 6656 exact
#define NB_WEMB   (TEMB * KPAD / 4 / 256)  // 768 exact
#define NB_CBUF   (TBF * KPAD / 4 / 256)   // 60 exact

__global__ void convgather_kernel(const float* __restrict__ Wqkv_s, const float* __restrict__ Wo_s,
                                  const float* __restrict__ Wqkv_t, const float* __restrict__ Wo_t,
                                  const float* __restrict__ W1, const float* __restrict__ W2,
                                  short* __restrict__ dst,
                                  const float* __restrict__ Wemb, short* __restrict__ wembbf,
                                  const float* __restrict__ src, const float* __restrict__ tgt,
                                  short* __restrict__ cbufbf) {
    int bx = blockIdx.x, tid = threadIdx.x;
    if (bx < NB_CONV) {
        size_t i = ((size_t)bx * 256 + tid) * 4;
        const float* s; size_t off;
        if (i < NW_QKV_S)       { s = Wqkv_s; off = i; }
        else if (i < OFF_QKV_T) { s = Wo_s;   off = i - OFF_O_S; }
        else if (i < OFF_O_T)   { s = Wqkv_t; off = i - OFF_QKV_T; }
        else if (i < OFF_W1)    { s = Wo_t;   off = i - OFF_O_T; }
        else if (i < OFF_W2)    { s = W1;     off = i - OFF_W1; }
        else                    { s = W2;     off = i - OFF_W2; }
        f4 v = *(const f4*)(s + off);
        s4 o = { f2bf(v[0]), f2bf(v[1]), f2bf(v[2]), f2bf(v[3]) };
        *(s4*)(dst + i) = o;
    } else if (bx < NB_CONV + NB_WEMB) {
        int g = (bx - NB_CONV) * 256 + tid;     // f4 group in [3072][256]
        int row = g >> 6;
        int colg = (g & 63) * 4;
        s4 o = {0, 0, 0, 0};
        if (colg < TD) {                         // colg<=212 -> 4 elems in range
            f4 v = *(const f4*)(Wemb + (size_t)row * TD + colg);
            o = { f2bf(v[0]), f2bf(v[1]), f2bf(v[2]), f2bf(v[3]) };
        }
        *(s4*)(wembbf + (size_t)row * KPAD + colg) = o;
    } else {
        int g = (bx - NB_CONV - NB_WEMB) * 256 + tid;  // f4 group in [240][256]
        int row = g >> 6;
        int colg = (g & 63) * 4;
        int b = row & 1, t = row >> 1;
        s4 o = {0, 0, 0, 0};
        if (colg < TD) {
            const float* sp = (t < 60) ? (src + ((size_t)b * 60 + t) * TD)
                                       : (tgt + ((size_t)b * 61 + (t - 60)) * TD);
            f4 v = *(const f4*)(sp + colg);
            o = { f2bf(v[0]), f2bf(v[1]), f2bf(v[2]), f2bf(v[3]) };
        }
        *(s4*)(cbufbf + (size_t)row * KPAD + colg) = o;
    }
}

// ---------------- MFMA building blocks ----------------
__device__ __forceinline__ void stage_bf(short* Ds, const short* __restrict__ src,
                                         size_t rstride, int nrows, int tid) {
    int r = tid >> 2, s = (tid & 3) * 32;
    short* d = Ds + r * LDT + s;
    if (r < nrows) {
        const short* p = src + (size_t)r * rstride + s;
        *(bf8*)(d)      = *(const bf8*)(p);
        *(bf8*)(d + 8)  = *(const bf8*)(p + 8);
        *(bf8*)(d + 16) = *(const bf8*)(p + 16);
        *(bf8*)(d + 24) = *(const bf8*)(p + 24);
    } else {
        bf8 z = {0,0,0,0,0,0,0,0};
        *(bf8*)(d) = z; *(bf8*)(d+8) = z; *(bf8*)(d+16) = z; *(bf8*)(d+24) = z;
    }
}

__device__ __forceinline__ void mfma_tile64(const short* As, const short* Bs,
                                            int wave, int lane, f4 acc[2][2]) {
    int wm = wave >> 1, wn = wave & 1;
    int lrow = lane & 15, lk = (lane >> 4) * 8;
    #pragma unroll
    for (int ks = 0; ks < 4; ++ks) {
        bf8 a0 = *(const bf8*)&As[(wm*32      + lrow) * LDT + ks*32 + lk];
        bf8 a1 = *(const bf8*)&As[(wm*32 + 16 + lrow) * LDT + ks*32 + lk];
        bf8 b0 = *(const bf8*)&Bs[(wn*32      + lrow) * LDT + ks*32 + lk];
        bf8 b1 = *(const bf8*)&Bs[(wn*32 + 16 + lrow) * LDT + ks*32 + lk];
        acc[0][0] = __builtin_amdgcn_mfma_f32_16x16x32_bf16(a0, b0, acc[0][0], 0, 0, 0);
        acc[0][1] = __builtin_amdgcn_mfma_f32_16x16x32_bf16(a0, b1, acc[0][1], 0, 0, 0);
        acc[1][0] = __builtin_amdgcn_mfma_f32_16x16x32_bf16(a1, b0, acc[1][0], 0, 0, 0);
        acc[1][1] = __builtin_amdgcn_mfma_f32_16x16x32_bf16(a1, b1, acc[1][1], 0, 0, 0);
    }
}

// ---------------- embedding MFMA GEMM + bias + PE ----------------
// grid (4, 48): M=240, N=3072, K=256 (zero-padded from 216), 2 chunks of 128.
__global__ __launch_bounds__(256) void mfma_embed_kernel(
        const short* __restrict__ cbufbf, const short* __restrict__ wembbf,
        const float* __restrict__ bemb, float* __restrict__ x0,
        short* __restrict__ x0bf, float* __restrict__ r0,
        short* __restrict__ r0bf) {
    __shared__ short As[64 * LDT], Bs[64 * LDT];
    int tid = threadIdx.x;
    int m0 = blockIdx.x * 64, n0 = blockIdx.y * 64;
    int mrem = TBF - m0; if (mrem > 64) mrem = 64;
    int wave = tid >> 6, lane = tid & 63;
    f4 acc[2][2] = {{{0,0,0,0},{0,0,0,0}},{{0,0,0,0},{0,0,0,0}}};
    #pragma unroll
    for (int kk = 0; kk < 2; ++kk) {
        stage_bf(As, cbufbf + (size_t)m0 * KPAD + kk * 128, KPAD, mrem, tid);
        stage_bf(Bs, wembbf + (size_t)n0 * KPAD + kk * 128, KPAD, 64, tid);
        __syncthreads();
        mfma_tile64(As, Bs, wave, lane, acc);
        __syncthreads();
    }
    int wm = wave >> 1, wn = wave & 1, lrow = lane & 15, gr = (lane >> 4) * 4;
    #pragma unroll
    for (int ni = 0; ni < 2; ++ni) {
        int col = n0 + wn*32 + ni*16 + lrow;
        float bv = bemb[col];
        float freq = expf((float)(col & ~1) * (-9.2103403719761836f / 3072.0f));
        float peodd = (col & 1) ? 1.f : 0.f;
        #pragma unroll
        for (int mi = 0; mi < 2; ++mi)
            #pragma unroll
            for (int rg = 0; rg < 4; ++rg) {
                int tr = wm*32 + mi*16 + gr + rg;
                if (tr < mrem) {
                    int grow = m0 + tr;
                    int t = grow >> 1;
                    float ang = (float)t * freq;
                    float pe = peodd ? cosf(ang) : sinf(ang);
                    float v = acc[mi][ni][rg] + bv + pe;
                    size_t off = (size_t)grow * TEMB + col;
                    x0[off] = v;
                    r0[off] = v;
                    short bvs = f2bf(v);
                    x0bf[off] = bvs;
                    r0bf[off] = bvs;
                }
            }
    }
}

// ---------------- mega QKV ----------------
// Temporal outputs head-major: [(b*TJ+j)*TNH+head][t][d]. Spatial frame-major.
__global__ __launch_bounds__(256) void mfma_qkvmega_kernel(
        const short* __restrict__ A2, const short* __restrict__ A3,
        const short* __restrict__ Wt, const short* __restrict__ Ws,
        const float* __restrict__ bt, const float* __restrict__ bs,
        float* __restrict__ Qp2, float* __restrict__ Kb2, float* __restrict__ Vb2,
        float* __restrict__ Qs_, float* __restrict__ Ks_, float* __restrict__ Vs_,
        float* __restrict__ Qt_, float* __restrict__ Kt_, float* __restrict__ Vt_,
        int p2n, int n0base) {
    __shared__ short As[64 * LDT], Bs[64 * LDT];
    int tid = threadIdx.x;
    int m0 = blockIdx.x * 64, j = blockIdx.z, yy = blockIdx.y;
    int mrem = TBF - m0; if (mrem > 64) mrem = 64;
    const short* Abf; const short* Wbf; const float* bias; int bofs, n0;
    float *dq, *dk, *dv;
    int headmajor;
    if (yy < p2n) {
        n0 = n0base + yy * 64;
        Abf = A2;
        Wbf = Wt + (size_t)j * 3 * TH * TH + (size_t)n0 * TH;
        bias = bt; bofs = j * 3 * TH;
        dq = Qp2; dk = Kb2; dv = Vb2;
        headmajor = 1;
    } else {
        int y2 = yy - p2n;
        int tmp = (y2 >= 6);
        n0 = (tmp ? y2 - 6 : y2) * 64;
        Abf = A3;
        if (tmp) { Wbf = Wt + (size_t)j * 3 * TH * TH + (size_t)n0 * TH; bias = bt; bofs = j * 3 * TH;
                   dq = Qt_; dk = Kt_; dv = Vt_; headmajor = 1; }
        else     { Wbf = Ws + (size_t)n0 * TH; bias = bs; bofs = 0;
                   dq = Qs_; dk = Ks_; dv = Vs_; headmajor = 0; }
    }
    stage_bf(As, Abf + (size_t)m0 * TEMB + j * TH, TEMB, mrem, tid);
    stage_bf(Bs, Wbf, TH, 64, tid);
    __syncthreads();
    int wave = tid >> 6, lane = tid & 63;
    f4 acc[2][2] = {{{0,0,0,0},{0,0,0,0}},{{0,0,0,0},{0,0,0,0}}};
    mfma_tile64(As, Bs, wave, lane, acc);
    int wm = wave >> 1, wn = wave & 1, lrow = lane & 15, gr = (lane >> 4) * 4;
    float* dst = (n0 < TH) ? dq : ((n0 < 2 * TH) ? dk : dv);
    int cb = n0 & (TH - 1);
    #pragma unroll
    for (int ni = 0; ni < 2; ++ni) {
        float bv = bias[bofs + n0 + wn*32 + ni*16 + lrow];
        int col = cb + wn*32 + ni*16 + lrow;
        #pragma unroll
        for (int mi = 0; mi < 2; ++mi)
            #pragma unroll
            for (int rg = 0; rg < 4; ++rg) {
                int tr = wm*32 + mi*16 + gr + rg;
                if (tr < mrem) {
                    int row = m0 + tr;
                    float v = acc[mi][ni][rg] + bv;
                    if (headmajor) {
                        int bb = row & 1, tt = row >> 1;
                        int hd = col >> 4, dd = col & 15;
                        dst[((size_t)((bb * TJ + j) * TNH + hd) * TW + tt) * THD + dd] = v;
                    } else {
                        dst[(size_t)(row * TJ + j) * TH + col] = v;
                    }
                }
            }
    }
}

// ---------------- mega attention: spatial (240) + temporal (384) -------------
// 512 threads/block. Temporal: block = (b,j,head), 8 waves; the two 120-key
// tasks (causal q-hi, special q-hi) are SPLIT across two waves each
// (keys 0-59 / 60-119) with an LDS partial combine, halving the per-block
// critical path. Wave map: 0=C-lo, 1=C-hi k0-59 (partial), 2=C-hi k60-119
// (combine+write), 3=S-lo+diag, 4=S-hi k0-59 (partial), 5=S-hi k60-119
// (+diag, combine+write), 6/7 idle. Barriers are wave-uniform.
__global__ __launch_bounds__(512) void attn_mega_kernel(
        const float* __restrict__ Qc_g, const float* __restrict__ Kc_g, const float* __restrict__ Vc_g,
        const float* __restrict__ Qs_g, const float* __restrict__ Ks_g, const float* __restrict__ Vs_g,
        const float* __restrict__ Qt_g, const float* __restrict__ Kt_g, const float* __restrict__ Vt_g,
        short* __restrict__ Oc, short* __restrict__ Os, short* __restrict__ Ot,
        int docausal) {
    __shared__ __align__(16) float smem[3 * TJ * SPAD];
    int bx = blockIdx.x;
    int tid = threadIdx.x;

    if (bx < 240) {
        // ---- spatial (frame-major inputs); all 512 threads stage, 192 compute
        float* Qs = smem;
        float* Ks = smem + TJ * SPAD;
        float* Vs = smem + 2 * TJ * SPAD;
        int b = bx & 1, t = bx >> 1;
        int base = (t * TB + b) * TJ;
        for (int i = tid; i < TJ * 32; i += 512) {
            int rr = i >> 5, c4 = i & 31;
            ((f4*)(Qs + rr * SPAD))[c4] = ((const f4*)(Qs_g + (size_t)(base + rr) * TH))[c4];
            ((f4*)(Ks + rr * SPAD))[c4] = ((const f4*)(Ks_g + (size_t)(base + rr) * TH))[c4];
            ((f4*)(Vs + rr * SPAD))[c4] = ((const f4*)(Vs_g + (size_t)(base + rr) * TH))[c4];
        }
        __syncthreads();
        if (tid >= 192) return;          // no barriers after this point
        int qj = tid % TJ;
        int head = tid / TJ;
        int hb = head * THD;
        float qv[THD];
        #pragma unroll
        for (int u = 0; u < THD; ++u) qv[u] = Qs[qj * SPAD + hb + u];
        float sc[TJ];
        float m = -1e30f;
        #pragma unroll
        for (int k = 0; k < TJ; ++k) {
            float a = 0.f;
            #pragma unroll
            for (int u = 0; u < THD; ++u) a += qv[u] * Ks[k * SPAD + hb + u];
            sc[k] = a * 0.25f;
            m = fmaxf(m, sc[k]);
        }
        float sum = 0.f;
        #pragma unroll
        for (int k = 0; k < TJ; ++k) { sc[k] = __expf(sc[k] - m); sum += sc[k]; }
        float inv = 1.0f / sum;
        float o[THD];
        #pragma unroll
        for (int u = 0; u < THD; ++u) o[u] = 0.f;
        #pragma unroll
        for (int k = 0; k < TJ; ++k) {
            #pragma unroll
            for (int u = 0; u < THD; ++u) o[u] += sc[k] * Vs[k * SPAD + hb + u];
        }
        size_t off = (size_t)(base + qj) * TH + hb;
        #pragma unroll
        for (int u = 0; u < THD; ++u) Os[off + u] = f2bf(o[u] * inv);
        return;
    }

    // ---- temporal: block = (b,j,head), 8 waves, key-split ----
    int cx = bx - 240;                    // 0..383
    int head = cx & 7;
    int j = (cx >> 3) % TJ;
    int b = (cx >> 3) / TJ;
    size_t base = (size_t)((b * TJ + j) * TNH + head) * HSEG;
    float* Kb = smem;                     // 120*16 = 1920 floats
    float* Vb = smem + 1920;              // 1920 floats
    float* pbuf = smem + 3840;            // 2*60*20 = 2400 floats (f4-aligned rows)
    for (int i = tid; i < 480; i += 512) {
        ((f4*)Kb)[i] = ((const f4*)(Kc_g + base))[i];
        ((f4*)Vb)[i] = ((const f4*)(Vc_g + base))[i];
    }
    __syncthreads();
    int wave = tid >> 6, lane = tid & 63;
    int iscausal = (wave < 3);
    int active = (wave < 6) && (docausal || !iscausal);
    int qhi = (wave == 1 || wave == 2 || wave == 4 || wave == 5);
    int act = (lane < 60);
    int q = (qhi ? 60 : 0) + (act ? lane : 59);
    int k0 = (wave == 2 || wave == 5) ? 60 : 0;
    int hasdiag = (wave == 3 || wave == 5);
    f4 a0 = {0,0,0,0}, a1 = {0,0,0,0}, a2 = {0,0,0,0}, a3 = {0,0,0,0};
    float sum = 0.f;
    if (active) {
        const float* Qg = iscausal ? Qc_g : Qt_g;
        f4 Qr0 = *(const f4*)(Qg + base + (size_t)q * THD);
        f4 Qr1 = *(const f4*)(Qg + base + (size_t)q * THD + 4);
        f4 Qr2 = *(const f4*)(Qg + base + (size_t)q * THD + 8);
        f4 Qr3 = *(const f4*)(Qg + base + (size_t)q * THD + 12);
        int qc = iscausal ? q : (q - 1);  // last valid baseline key
        #pragma unroll 4
        for (int k = k0; k < k0 + 60; ++k) {
            const float* kr = Kb + k * 16;
            f4 d = Qr0 * ((const f4*)kr)[0] + Qr1 * ((const f4*)kr)[1]
                 + Qr2 * ((const f4*)kr)[2] + Qr3 * ((const f4*)kr)[3];
            float s = (d[0] + d[1] + d[2] + d[3]) * 0.25f;
            float p = (k <= qc) ? __expf(s) : 0.f;
            sum += p;
            const float* vr = Vb + k * 16;
            a0 += p * ((const f4*)vr)[0];
            a1 += p * ((const f4*)vr)[1];
            a2 += p * ((const f4*)vr)[2];
            a3 += p * ((const f4*)vr)[3];
        }
        if (hasdiag) {                    // diagonal from lane-private special K/V
            f4 Ks0 = *(const f4*)(Kt_g + base + (size_t)q * THD);
            f4 Ks1 = *(const f4*)(Kt_g + base + (size_t)q * THD + 4);
            f4 Ks2 = *(const f4*)(Kt_g + base + (size_t)q * THD + 8);
            f4 Ks3 = *(const f4*)(Kt_g + base + (size_t)q * THD + 12);
            f4 Vd0 = *(const f4*)(Vt_g + base + (size_t)q * THD);
            f4 Vd1 = *(const f4*)(Vt_g + base + (size_t)q * THD + 4);
            f4 Vd2 = *(const f4*)(Vt_g + base + (size_t)q * THD + 8);
            f4 Vd3 = *(const f4*)(Vt_g + base + (size_t)q * THD + 12);
            f4 d = Qr0 * Ks0 + Qr1 * Ks1 + Qr2 * Ks2 + Qr3 * Ks3;
            float p = __expf((d[0] + d[1] + d[2] + d[3]) * 0.25f);
            sum += p;
            a0 += p * Vd0; a1 += p * Vd1; a2 += p * Vd2; a3 += p * Vd3;
        }
    }
    if (active && act && (wave == 1 || wave == 4)) {
        float* p = pbuf + ((wave == 4 ? 60 : 0) + lane) * 20;
        *(f4*)(p) = a0; *(f4*)(p + 4) = a1; *(f4*)(p + 8) = a2; *(f4*)(p + 12) = a3;
        p[16] = sum;
    }
    __syncthreads();                      // uniform: all 8 waves arrive
    if (active && act && (wave == 0 || wave == 2 || wave == 3 || wave == 5)) {
        if (wave == 2 || wave == 5) {     // merge partner's keys 0-59 partial
            const float* p = pbuf + ((wave == 5 ? 60 : 0) + lane) * 20;
            a0 += *(const f4*)(p); a1 += *(const f4*)(p + 4);
            a2 += *(const f4*)(p + 8); a3 += *(const f4*)(p + 12);
            sum += p[16];
        }
        float inv = 1.0f / sum;
        short* O = iscausal ? Oc : Ot;
        size_t off = (size_t)((q * TB + b) * TJ + j) * TH + head * THD;
        s4 o0 = { f2bf(a0[0]*inv), f2bf(a0[1]*inv), f2bf(a0[2]*inv), f2bf(a0[3]*inv) };
        s4 o1 = { f2bf(a1[0]*inv), f2bf(a1[1]*inv), f2bf(a1[2]*inv), f2bf(a1[3]*inv) };
        s4 o2 = { f2bf(a2[0]*inv), f2bf(a2[1]*inv), f2bf(a2[2]*inv), f2bf(a2[3]*inv) };
        s4 o3 = { f2bf(a3[0]*inv), f2bf(a3[1]*inv), f2bf(a3[2]*inv), f2bf(a3[3]*inv) };
        *(s4*)(O + off)      = o0;
        *(s4*)(O + off + 4)  = o1;
        *(s4*)(O + off + 8)  = o2;
        *(s4*)(O + off + 12) = o3;
    }
}

// ---------------- OLN compute core ----------------
__device__ __forceinline__ void oln_compute(
        const short* __restrict__ Abf, const short* __restrict__ Wbf,
        const float* __restrict__ bias, const float* __restrict__ resid,
        const float* __restrict__ g, const float* __restrict__ bln,
        int perJoint, int m0, int j,
        short* As, short* Bs, float* rsum, float* rsq, float* lnm, float* lnr,
        float o0[4], float o1[4]) {
    int tid = threadIdx.x;
    { int r = tid >> 4, s = (tid & 15) * 8;
      *(bf8*)&As[r * LDT + s] = *(const bf8*)(Abf + (size_t)(m0 + r) * TEMB + j * TH + s); }
    { int r = tid >> 1, s = (tid & 1) * 64;
      const short* p = Wbf + (perJoint ? (size_t)j * TH * TH : 0) + (size_t)r * TH + s;
      short* d = &Bs[r * LDT + s];
      #pragma unroll
      for (int cc = 0; cc < 64; cc += 8) *(bf8*)(d + cc) = *(const bf8*)(p + cc); }
    __syncthreads();
    int wave = tid >> 6, lane = tid & 63, lrow = lane & 15, lk = (lane >> 4) * 8, gr = (lane >> 4) * 4;
    f4 acc[2] = {{0,0,0,0},{0,0,0,0}};
    #pragma unroll
    for (int ks = 0; ks < 4; ++ks) {
        bf8 a  = *(const bf8*)&As[lrow * LDT + ks*32 + lk];
        bf8 b0 = *(const bf8*)&Bs[(wave*32      + lrow) * LDT + ks*32 + lk];
        bf8 b1 = *(const bf8*)&Bs[(wave*32 + 16 + lrow) * LDT + ks*32 + lk];
        acc[0] = __builtin_amdgcn_mfma_f32_16x16x32_bf16(a, b0, acc[0], 0, 0, 0);
        acc[1] = __builtin_amdgcn_mfma_f32_16x16x32_bf16(a, b1, acc[1], 0, 0, 0);
    }
    int col0 = wave*32 + lrow, col1 = col0 + 16;
    int bofs = perJoint ? j * TH : 0;
    float bv0 = bias[bofs + col0], bv1 = bias[bofs + col1];
    float v0[4], v1[4], sr_[4], sq_[4];
    #pragma unroll
    for (int rg = 0; rg < 4; ++rg) {
        size_t ro = (size_t)(m0 + gr + rg) * TEMB + j * TH;
        v0[rg] = acc[0][rg] + bv0 + resid[ro + col0];
        v1[rg] = acc[1][rg] + bv1 + resid[ro + col1];
        sr_[rg] = v0[rg] + v1[rg];
        sq_[rg] = v0[rg]*v0[rg] + v1[rg]*v1[rg];
    }
    #pragma unroll
    for (int o = 1; o < 16; o <<= 1) {
        #pragma unroll
        for (int rg = 0; rg < 4; ++rg) { sr_[rg] += __shfl_xor(sr_[rg], o); sq_[rg] += __shfl_xor(sq_[rg], o); }
    }
    if (lrow == 0) {
        #pragma unroll
        for (int rg = 0; rg < 4; ++rg) { rsum[wave*16 + gr + rg] = sr_[rg]; rsq[wave*16 + gr + rg] = sq_[rg]; }
    }
    __syncthreads();
    if (tid < 16) {
        float s = rsum[tid] + rsum[16 + tid] + rsum[32 + tid] + rsum[48 + tid];
        float q = rsq[tid] + rsq[16 + tid] + rsq[32 + tid] + rsq[48 + tid];
        float mean = s * (1.0f / TH);
        float var = q * (1.0f / TH) - mean * mean;
        lnm[tid] = mean; lnr[tid] = rsqrtf(var + 1e-5f);
    }
    __syncthreads();
    float g0 = g[col0], g1 = g[col1], l0 = bln[col0], l1 = bln[col1];
    #pragma unroll
    for (int rg = 0; rg < 4; ++rg) {
        int row = gr + rg;
        float mean = lnm[row], rs = lnr[row];
        o0[rg] = (v0[rg] - mean) * rs * g0 + l0;
        o1[rg] = (v1[rg] - mean) * rs * g1 + l1;
    }
}

// fused OLN: part2-temporal (np2 blocks) + part3 spatial+temporal (360 blocks)
__global__ __launch_bounds__(256) void mfma_olnfused_kernel(
        const short* __restrict__ A2, const short* __restrict__ Wt,
        const float* __restrict__ bt, const float* __restrict__ res2,
        const float* __restrict__ tg, const float* __restrict__ tl,
        short* __restrict__ Yb2,
        const short* __restrict__ A3s, const short* __restrict__ Ws,
        const float* __restrict__ bs, const short* __restrict__ A3t,
        const float* __restrict__ res3,
        const float* __restrict__ sg, const float* __restrict__ sl,
        short* __restrict__ Yb3, int np2) {
    __shared__ short As[16 * LDT];
    __shared__ short Bs[128 * LDT];
    __shared__ float rsum[64], rsq[64], lnm[16], lnr[16];
    int bx = blockIdx.x;
    int tid = threadIdx.x;
    int wave = tid >> 6, lane = tid & 63, lrow = lane & 15, gr = (lane >> 4) * 4;
    int col0 = wave*32 + lrow, col1 = col0 + 16;
    if (bx < np2) {
        int m0 = (bx % 15) * 16, j = bx / 15;
        float o0[4], o1[4];
        oln_compute(A2, Wt, bt, res2, tg, tl, 1, m0, j,
                    As, Bs, rsum, rsq, lnm, lnr, o0, o1);
        #pragma unroll
        for (int rg = 0; rg < 4; ++rg) {
            size_t ro = (size_t)(m0 + gr + rg) * TEMB + j * TH;
            Yb2[ro + col0] = f2bf(o0[rg]);
            Yb2[ro + col1] = f2bf(o1[rg]);
        }
    } else {
        int idx = bx - np2;
        int m0 = (idx % 15) * 16, j = idx / 15;
        float s0[4], s1[4], t0[4], t1[4];
        oln_compute(A3s, Ws, bs, res3, sg, sl, 0, m0, j,
                    As, Bs, rsum, rsq, lnm, lnr, s0, s1);
        __syncthreads();
        oln_compute(A3t, Wt, bt, res3, tg, tl, 1, m0, j,
                    As, Bs, rsum, rsq, lnm, lnr, t0, t1);
        #pragma unroll
        for (int rg = 0; rg < 4; ++rg) {
            size_t ro = (size_t)(m0 + gr + rg) * TEMB + j * TH;
            Yb3[ro + col0] = f2bf(t0[rg] + s0[rg]);
            Yb3[ro + col1] = f2bf(t1[rg] + s1[rg]);
        }
    }
}

// ---------------- FFN MFMA GEMMs ----------------
__global__ __launch_bounds__(256) void mfma_ffn1_kernel(
        const short* __restrict__ Ybf, const short* __restrict__ W1bf,
        const float* __restrict__ b1, short* __restrict__ Fb) {
    __shared__ short As[64 * LDT], Bs[64 * LDT];
    int tid = threadIdx.x;
    int m0 = blockIdx.x * 64, n0 = blockIdx.y * 64;
    stage_bf(As, Ybf + (size_t)m0 * TH, TH, 64, tid);
    stage_bf(Bs, W1bf + (size_t)n0 * TH, TH, 64, tid);
    __syncthreads();
    int wave = tid >> 6, lane = tid & 63;
    f4 acc[2][2] = {{{0,0,0,0},{0,0,0,0}},{{0,0,0,0},{0,0,0,0}}};
    mfma_tile64(As, Bs, wave, lane, acc);
    int wm = wave >> 1, wn = wave & 1, lrow = lane & 15, gr = (lane >> 4) * 4;
    #pragma unroll
    for (int ni = 0; ni < 2; ++ni) {
        int col = n0 + wn*32 + ni*16 + lrow;
        float bv = b1[col];
        #pragma unroll
        for (int mi = 0; mi < 2; ++mi)
            #pragma unroll
            for (int rg = 0; rg < 4; ++rg) {
                int tr = wm*32 + mi*16 + gr + rg;
                float v = 2.0f * fmaxf(acc[mi][ni][rg] + bv, 0.0f);
                Fb[(size_t)(m0 + tr) * TF + col] = f2bf(v);
            }
    }
}

// rows < splitrow -> OutA (f32+bf16); rows >= splitrow -> OutB[row-splitrow]
__global__ __launch_bounds__(256) void mfma_ffn2_kernel(
        const short* __restrict__ Fb, const short* __restrict__ W2bf,
        const float* __restrict__ b2, float* __restrict__ OutAf,
        short* __restrict__ OutAbf, float* __restrict__ OutBf,
        short* __restrict__ OutBbf, int splitrow) {
    __shared__ short As[64 * LDT], Bs[64 * LDT];
    int tid = threadIdx.x;
    int m0 = blockIdx.x * 64, n0 = blockIdx.y * 64;
    int wave = tid >> 6, lane = tid & 63;
    f4 acc[2][2] = {{{0,0,0,0},{0,0,0,0}},{{0,0,0,0},{0,0,0,0}}};
    #pragma unroll
    for (int kk = 0; kk < 2; ++kk) {
        stage_bf(As, Fb + (size_t)m0 * TF + kk * 128, TF, 64, tid);
        stage_bf(Bs, W2bf + (size_t)n0 * TF + kk * 128, TF, 64, tid);
        __syncthreads();
        mfma_tile64(As, Bs, wave, lane, acc);
        __syncthreads();
    }
    int wm = wave >> 1, wn = wave & 1, lrow = lane & 15, gr = (lane >> 4) * 4;
    #pragma unroll
    for (int ni = 0; ni < 2; ++ni) {
        int col = n0 + wn*32 + ni*16 + lrow;
        float bv = b2[col];
        #pragma unroll
        for (int mi = 0; mi < 2; ++mi)
            #pragma unroll
            for (int rg = 0; rg < 4; ++rg) {
                int tr = wm*32 + mi*16 + gr + rg;
                int row = m0 + tr;
                float v = acc[mi][ni][rg] + bv;
                if (row < splitrow) {
                    size_t off = (size_t)row * TH + col;
                    OutAf[off] = v; OutAbf[off] = f2bf(v);
                } else {
                    size_t off = (size_t)(row - splitrow) * TH + col;
                    OutBf[off] = v; OutBbf[off] = f2bf(v);
                }
            }
    }
}

// ---------------- final projection + residual ----------------
__global__ void final_kernel(const float* __restrict__ r4, const float* __restrict__ Wout,
                             const float* __restrict__ bout, const float* __restrict__ src,
                             const float* __restrict__ tgt, float* __restrict__ out) {
    int idx = blockIdx.x * 256 + threadIdx.x;
    if (idx >= TB * TW * TD) return;
    int d = idx % TD;
    int t = (idx / TD) % TW;
    int b = idx / (TD * TW);
    int j = d / 9, o = d % 9;
    const float* rr = r4 + (size_t)((t * TB + b) * TJ + j) * TH;
    const float* wt = Wout + (size_t)o * TH;
    float acc = bout[o];
    #pragma unroll 4
    for (int h = 0; h < TH; ++h) acc += rr[h] * wt[h];
    float cv = (t < 60) ? src[((size_t)b * 60 + t) * TD + d]
                        : tgt[((size_t)b * 61 + (t - 60)) * TD + d];
    out[idx] = acc + cv;
}

extern "C" void kernel_launch(void* const* d_in, const int* in_sizes, int n_in,
                              void* d_out, int out_size, void* d_ws, size_t ws_size,
                              hipStream_t stream) {
    const float* src    = (const float*)d_in[0];
    const float* tgt    = (const float*)d_in[1];
    const float* Wemb   = (const float*)d_in[2];
    const float* bemb   = (const float*)d_in[3];
    const float* Wqkv_s = (const float*)d_in[4];
    const float* bqkv_s = (const float*)d_in[5];
    const float* Wo_s   = (const float*)d_in[6];
    const float* bo_s   = (const float*)d_in[7];
    const float* sn_g   = (const float*)d_in[8];
    const float* sn_b   = (const float*)d_in[9];
    const float* Wqkv_t = (const float*)d_in[10];
    const float* bqkv_t = (const float*)d_in[11];
    const float* Wo_t   = (const float*)d_in[12];
    const float* bo_t   = (const float*)d_in[13];
    const float* tn_g   = (const float*)d_in[14];
    const float* tn_b   = (const float*)d_in[15];
    const float* W1     = (const float*)d_in[16];
    const float* b1     = (const float*)d_in[17];
    const float* W2     = (const float*)d_in[18];
    const float* b2     = (const float*)d_in[19];
    const float* Wout   = (const float*)d_in[20];
    const float* bout   = (const float*)d_in[21];
    float* out = (float*)d_out;

    const size_t RH = (size_t)TROWS * TH;   // 737280
    float* f = (float*)d_ws;
    float* x0    = f;
    float* Kbase = x0 + RH;              // 4*RH (head-major per layer)
    float* Vbase = Kbase + 4 * RH;       // 4*RH
    float* r     = Vbase + 4 * RH;
    float* Qp2   = r + RH;
    float* Qs    = Qp2 + RH;
    float* Ks    = Qs + RH;
    float* Vs    = Ks + RH;
    float* Qt    = Vs + RH;
    float* Kt    = Qt + RH;
    float* Vt    = Kt + RH;
    float* Bb0   = Vt + RH;
    float* Bb1   = Bb0 + RH;
    short* sbase   = (short*)(Bb1 + RH);
    short* x0bf    = sbase;
    short* rbf     = x0bf + RH;
    short* attnb_c = rbf + RH;
    short* attnb_s = attnb_c + RH;
    short* attnb_t = attnb_s + RH;
    short* yball   = attnb_t + RH;       // 2*RH (part2 lower, part3 upper)
    short* fball   = yball + 2 * RH;     // 2*TROWS*TF
    short* Bb0bf   = fball + 2 * (size_t)TROWS * TF;
    short* Bb1bf   = Bb0bf + RH;
    short* wbf     = Bb1bf + RH;         // NW_TOT shorts
    short* wembbf  = wbf + NW_TOT;       // TEMB*KPAD shorts
    short* cbufbf  = wembbf + (size_t)TEMB * KPAD;  // TBF*KPAD shorts

    const short* wqkvs_bf = wbf;
    const short* wos_bf   = wbf + OFF_O_S;
    const short* wqkvt_bf = wbf + OFF_QKV_T;
    const short* wot_bf   = wbf + OFF_O_T;
    const short* w1bf     = wbf + OFF_W1;
    const short* w2bf     = wbf + OFF_W2;

    // 0. weights -> bf16 (incl. padded Wemb) + gather concat -> padded bf16
    convgather_kernel<<<NB_CONV + NB_WEMB + NB_CBUF, 256, 0, stream>>>(
        Wqkv_s, Wo_s, Wqkv_t, Wo_t, W1, W2, wbf,
        Wemb, wembbf, src, tgt, cbufbf);

    // 1. embedding MFMA GEMM (+bias+PE); writes x0/x0bf and r/rbf
    mfma_embed_kernel<<<dim3(4, 48), 256, 0, stream>>>(
        cbufbf, wembbf, bemb, x0, x0bf, r, rbf);

    // 2+3. per-layer mega launches
    const float* Binf = x0;
    const short* Binbf = x0bf;
    for (int l = 0; l < 4; ++l) {
        int p2n = (l < 3) ? 6 : 4;
        int n0base = (l < 3) ? 0 : 128;
        int np2 = (l < 3) ? 360 : 0;
        const short* wt_l = wqkvt_bf + (size_t)l * TJ * 3 * TH * TH;
        const short* ws_l = wqkvs_bf + (size_t)l * 3 * TH * TH;
        const float* bt_l = bqkv_t + (size_t)l * TJ * 3 * TH;
        const float* bs_l = bqkv_s + (size_t)l * 3 * TH;

        mfma_qkvmega_kernel<<<dim3(4, p2n + 12, 24), 256, 0, stream>>>(
            Binbf, rbf, wt_l, ws_l, bt_l, bs_l,
            Qp2, Kbase + l * RH, Vbase + l * RH,
            Qs, Ks, Vs, Qt, Kt, Vt, p2n, n0base);

        attn_mega_kernel<<<240 + 384, 512, 0, stream>>>(
            Qp2, Kbase + l * RH, Vbase + l * RH,
            Qs, Ks, Vs, Qt, Kt, Vt,
            attnb_c, attnb_s, attnb_t, (l < 3) ? 1 : 0);

        mfma_olnfused_kernel<<<np2 + 360, 256, 0, stream>>>(
            attnb_c, wot_bf + (size_t)l * TJ * TH * TH, bo_t + (size_t)l * TJ * TH,
            Binf, tn_g + l * TH, tn_b + l * TH, yball,
            attnb_s, wos_bf + (size_t)l * TH * TH, bo_s + (size_t)l * TH,
            attnb_t, r, sn_g + l * TH, sn_b + l * TH, yball + RH, np2);

        if (l < 3) {
            mfma_ffn1_kernel<<<dim3(180, 4), 256, 0, stream>>>(
                yball, w1bf + (size_t)l * TF * TH, b1 + l * TF, fball);
            float* Boutf = (l & 1) ? Bb1 : Bb0;
            short* Boutbf = (l & 1) ? Bb1bf : Bb0bf;
            mfma_ffn2_kernel<<<dim3(180, 2), 256, 0, stream>>>(
                fball, w2bf + (size_t)l * TH * TF, b2 + l * TH,
                Boutf, Boutbf, r, rbf, TROWS);
            Binf = Boutf; Binbf = Boutbf;
        } else {
            mfma_ffn1_kernel<<<dim3(90, 4), 256, 0, stream>>>(
                yball + RH, w1bf + (size_t)l * TF * TH, b1 + l * TF, fball);
            mfma_ffn2_kernel<<<dim3(90, 2), 256, 0, stream>>>(
                fball, w2bf + (size_t)l * TH * TF, b2 + l * TH,
                r, rbf, r, rbf, 0);
        }
    }

    // 4. output projection + residual
    final_kernel<<<(TB * TW * TD + 255) / 256, 256, 0, stream>>>(r, Wout, bout, src, tgt, out);
}

// Round 26
// 250.053 us; speedup vs baseline: 1.0565x; 1.0013x over previous
//
#include <hip/hip_runtime.h>

// Sizes
#define TW 120
#define TB 2
#define TJ 24
#define TH 128
#define TNH 8
#define THD 16
#define TF 256
#define TD 216
#define TROWS (TW*TB*TJ)   // 5760
#define TEMB (TJ*TH)       // 3072
#define TBF 240
#define KPAD 256           // padded K for embed MFMA (2 chunks of 128)

#define QCH 60
#define LDT 136    // bf16 MFMA LDS row stride (shorts)
#define SPAD (TH + 4)
#define HSEG (TW*THD)      // 1920 floats per (b,j,head) segment

typedef float f4 __attribute__((ext_vector_type(4)));
typedef short bf8 __attribute__((ext_vector_type(8)));
typedef short s4 __attribute__((ext_vector_type(4)));

__device__ __forceinline__ short f2bf(float x) {
    union { float f; unsigned u; } v; v.f = x;
    unsigned r = (v.u + 0x7FFFu + ((v.u >> 16) & 1u)) >> 16;
    return (short)r;
}

// ---------------- weight conversion + gathers (fused) ----------------
#define NW_QKV_S 196608
#define NW_O_S    65536
#define NW_QKV_T 4718592
#define NW_O_T   1572864
#define NW_1      131072
#define NW_2      131072
#define OFF_O_S   (NW_QKV_S)
#define OFF_QKV_T (OFF_O_S + NW_O_S)
#define OFF_O_T   (OFF_QKV_T + NW_QKV_T)
#define OFF_W1    (OFF_O_T + NW_O_T)
#define OFF_W2    (OFF_W1 + NW_1)
#define NW_TOT    (OFF_W2 + NW_2)      // 6815744
#define NB_CONV   (NW_TOT / 4 / 256)   // 6656 exact
#define NB_WEMB   (TEMB * KPAD / 4 / 256)  // 768 exact
#define NB_CBUF   (TBF * KPAD / 4 / 256)   // 60 exact

__global__ void convgather_kernel(const float* __restrict__ Wqkv_s, const float* __restrict__ Wo_s,
                                  const float* __restrict__ Wqkv_t, const float* __restrict__ Wo_t,
                                  const float* __restrict__ W1, const float* __restrict__ W2,
                                  short* __restrict__ dst,
                                  const float* __restrict__ Wemb, short* __restrict__ wembbf,
                                  const float* __restrict__ src, const float* __restrict__ tgt,
                                  short* __restrict__ cbufbf) {
    int bx = blockIdx.x, tid = threadIdx.x;
    if (bx < NB_CONV) {
        size_t i = ((size_t)bx * 256 + tid) * 4;
        const float* s; size_t off;
        if (i < NW_QKV_S)       { s = Wqkv_s; off = i; }
        else if (i < OFF_QKV_T) { s = Wo_s;   off = i - OFF_O_S; }
        else if (i < OFF_O_T)   { s = Wqkv_t; off = i - OFF_QKV_T; }
        else if (i < OFF_W1)    { s = Wo_t;   off = i - OFF_O_T; }
        else if (i < OFF_W2)    { s = W1;     off = i - OFF_W1; }
        else                    { s = W2;     off = i - OFF_W2; }
        f4 v = *(const f4*)(s + off);
        s4 o = { f2bf(v[0]), f2bf(v[1]), f2bf(v[2]), f2bf(v[3]) };
        *(s4*)(dst + i) = o;
    } else if (bx < NB_CONV + NB_WEMB) {
        int g = (bx - NB_CONV) * 256 + tid;     // f4 group in [3072][256]
        int row = g >> 6;
        int colg = (g & 63) * 4;
        s4 o = {0, 0, 0, 0};
        if (colg < TD) {                         // colg<=212 -> 4 elems in range
            f4 v = *(const f4*)(Wemb + (size_t)row * TD + colg);
            o = { f2bf(v[0]), f2bf(v[1]), f2bf(v[2]), f2bf(v[3]) };
        }
        *(s4*)(wembbf + (size_t)row * KPAD + colg) = o;
    } else {
        int g = (bx - NB_CONV - NB_WEMB) * 256 + tid;  // f4 group in [240][256]
        int row = g >> 6;
        int colg = (g & 63) * 4;
        int b = row & 1, t = row >> 1;
        s4 o = {0, 0, 0, 0};
        if (colg < TD) {
            const float* sp = (t < 60) ? (src + ((size_t)b * 60 + t) * TD)
                                       : (tgt + ((size_t)b * 61 + (t - 60)) * TD);
            f4 v = *(const f4*)(sp + colg);
            o = { f2bf(v[0]), f2bf(v[1]), f2bf(v[2]), f2bf(v[3]) };
        }
        *(s4*)(cbufbf + (size_t)row * KPAD + colg) = o;
    }
}

// ---------------- MFMA building blocks ----------------
__device__ __forceinline__ void stage_bf(short* Ds, const short* __restrict__ src,
                                         size_t rstride, int nrows, int tid) {
    int r = tid >> 2, s = (tid & 3) * 32;
    short* d = Ds + r * LDT + s;
    if (r < nrows) {
        const short* p = src + (size_t)r * rstride + s;
        *(bf8*)(d)      = *(const bf8*)(p);
        *(bf8*)(d + 8)  = *(const bf8*)(p + 8);
        *(bf8*)(d + 16) = *(const bf8*)(p + 16);
        *(bf8*)(d + 24) = *(const bf8*)(p + 24);
    } else {
        bf8 z = {0,0,0,0,0,0,0,0};
        *(bf8*)(d) = z; *(bf8*)(d+8) = z; *(bf8*)(d+16) = z; *(bf8*)(d+24) = z;
    }
}

__device__ __forceinline__ void mfma_tile64(const short* As, const short* Bs,
                                            int wave, int lane, f4 acc[2][2]) {
    int wm = wave >> 1, wn = wave & 1;
    int lrow = lane & 15, lk = (lane >> 4) * 8;
    #pragma unroll
    for (int ks = 0; ks < 4; ++ks) {
        bf8 a0 = *(const bf8*)&As[(wm*32      + lrow) * LDT + ks*32 + lk];
        bf8 a1 = *(const bf8*)&As[(wm*32 + 16 + lrow) * LDT + ks*32 + lk];
        bf8 b0 = *(const bf8*)&Bs[(wn*32      + lrow) * LDT + ks*32 + lk];
        bf8 b1 = *(const bf8*)&Bs[(wn*32 + 16 + lrow) * LDT + ks*32 + lk];
        acc[0][0] = __builtin_amdgcn_mfma_f32_16x16x32_bf16(a0, b0, acc[0][0], 0, 0, 0);
        acc[0][1] = __builtin_amdgcn_mfma_f32_16x16x32_bf16(a0, b1, acc[0][1], 0, 0, 0);
        acc[1][0] = __builtin_amdgcn_mfma_f32_16x16x32_bf16(a1, b0, acc[1][0], 0, 0, 0);
        acc[1][1] = __builtin_amdgcn_mfma_f32_16x16x32_bf16(a1, b1, acc[1][1], 0, 0, 0);
    }
}

// ---------------- embedding MFMA GEMM + bias + PE ----------------
// grid (4, 48): M=240, N=3072, K=256 (zero-padded from 216), 2 chunks of 128.
__global__ __launch_bounds__(256) void mfma_embed_kernel(
        const short* __restrict__ cbufbf, const short* __restrict__ wembbf,
        const float* __restrict__ bemb, float* __restrict__ x0,
        short* __restrict__ x0bf, float* __restrict__ r0,
        short* __restrict__ r0bf) {
    __shared__ short As[64 * LDT], Bs[64 * LDT];
    int tid = threadIdx.x;
    int m0 = blockIdx.x * 64, n0 = blockIdx.y * 64;
    int mrem = TBF - m0; if (mrem > 64) mrem = 64;
    int wave = tid >> 6, lane = tid & 63;
    f4 acc[2][2] = {{{0,0,0,0},{0,0,0,0}},{{0,0,0,0},{0,0,0,0}}};
    #pragma unroll
    for (int kk = 0; kk < 2; ++kk) {
        stage_bf(As, cbufbf + (size_t)m0 * KPAD + kk * 128, KPAD, mrem, tid);
        stage_bf(Bs, wembbf + (size_t)n0 * KPAD + kk * 128, KPAD, 64, tid);
        __syncthreads();
        mfma_tile64(As, Bs, wave, lane, acc);
        __syncthreads();
    }
    int wm = wave >> 1, wn = wave & 1, lrow = lane & 15, gr = (lane >> 4) * 4;
    #pragma unroll
    for (int ni = 0; ni < 2; ++ni) {
        int col = n0 + wn*32 + ni*16 + lrow;
        float bv = bemb[col];
        float freq = expf((float)(col & ~1) * (-9.2103403719761836f / 3072.0f));
        float peodd = (col & 1) ? 1.f : 0.f;
        #pragma unroll
        for (int mi = 0; mi < 2; ++mi)
            #pragma unroll
            for (int rg = 0; rg < 4; ++rg) {
                int tr = wm*32 + mi*16 + gr + rg;
                if (tr < mrem) {
                    int grow = m0 + tr;
                    int t = grow >> 1;
                    float ang = (float)t * freq;
                    float pe = peodd ? cosf(ang) : sinf(ang);
                    float v = acc[mi][ni][rg] + bv + pe;
                    size_t off = (size_t)grow * TEMB + col;
                    x0[off] = v;
                    r0[off] = v;
                    short bvs = f2bf(v);
                    x0bf[off] = bvs;
                    r0bf[off] = bvs;
                }
            }
    }
}

// ---------------- mega QKV ----------------
// Temporal outputs head-major: [(b*TJ+j)*TNH+head][t][d]. Spatial frame-major.
__global__ __launch_bounds__(256) void mfma_qkvmega_kernel(
        const short* __restrict__ A2, const short* __restrict__ A3,
        const short* __restrict__ Wt, const short* __restrict__ Ws,
        const float* __restrict__ bt, const float* __restrict__ bs,
        float* __restrict__ Qp2, float* __restrict__ Kb2, float* __restrict__ Vb2,
        float* __restrict__ Qs_, float* __restrict__ Ks_, float* __restrict__ Vs_,
        float* __restrict__ Qt_, float* __restrict__ Kt_, float* __restrict__ Vt_,
        int p2n, int n0base) {
    __shared__ short As[64 * LDT], Bs[64 * LDT];
    int tid = threadIdx.x;
    int m0 = blockIdx.x * 64, j = blockIdx.z, yy = blockIdx.y;
    int mrem = TBF - m0; if (mrem > 64) mrem = 64;
    const short* Abf; const short* Wbf; const float* bias; int bofs, n0;
    float *dq, *dk, *dv;
    int headmajor;
    if (yy < p2n) {
        n0 = n0base + yy * 64;
        Abf = A2;
        Wbf = Wt + (size_t)j * 3 * TH * TH + (size_t)n0 * TH;
        bias = bt; bofs = j * 3 * TH;
        dq = Qp2; dk = Kb2; dv = Vb2;
        headmajor = 1;
    } else {
        int y2 = yy - p2n;
        int tmp = (y2 >= 6);
        n0 = (tmp ? y2 - 6 : y2) * 64;
        Abf = A3;
        if (tmp) { Wbf = Wt + (size_t)j * 3 * TH * TH + (size_t)n0 * TH; bias = bt; bofs = j * 3 * TH;
                   dq = Qt_; dk = Kt_; dv = Vt_; headmajor = 1; }
        else     { Wbf = Ws + (size_t)n0 * TH; bias = bs; bofs = 0;
                   dq = Qs_; dk = Ks_; dv = Vs_; headmajor = 0; }
    }
    stage_bf(As, Abf + (size_t)m0 * TEMB + j * TH, TEMB, mrem, tid);
    stage_bf(Bs, Wbf, TH, 64, tid);
    __syncthreads();
    int wave = tid >> 6, lane = tid & 63;
    f4 acc[2][2] = {{{0,0,0,0},{0,0,0,0}},{{0,0,0,0},{0,0,0,0}}};
    mfma_tile64(As, Bs, wave, lane, acc);
    int wm = wave >> 1, wn = wave & 1, lrow = lane & 15, gr = (lane >> 4) * 4;
    float* dst = (n0 < TH) ? dq : ((n0 < 2 * TH) ? dk : dv);
    int cb = n0 & (TH - 1);
    #pragma unroll
    for (int ni = 0; ni < 2; ++ni) {
        float bv = bias[bofs + n0 + wn*32 + ni*16 + lrow];
        int col = cb + wn*32 + ni*16 + lrow;
        #pragma unroll
        for (int mi = 0; mi < 2; ++mi)
            #pragma unroll
            for (int rg = 0; rg < 4; ++rg) {
                int tr = wm*32 + mi*16 + gr + rg;
                if (tr < mrem) {
                    int row = m0 + tr;
                    float v = acc[mi][ni][rg] + bv;
                    if (headmajor) {
                        int bb = row & 1, tt = row >> 1;
                        int hd = col >> 4, dd = col & 15;
                        dst[((size_t)((bb * TJ + j) * TNH + hd) * TW + tt) * THD + dd] = v;
                    } else {
                        dst[(size_t)(row * TJ + j) * TH + col] = v;
                    }
                }
            }
    }
}

// ---------------- mega attention: spatial (240) + temporal (384) -------------
// 768 threads/block. Temporal: block = (b,j,head), 12 waves; the 360 total
// key-iterations are split into 12 chunks of 30: C-lo(w0-1), C-hi(w2-5),
// S-lo(w6-7), S-hi(w8-11). Writer = last chunk of each task (w1,w5,w7,w11)
// merges partner partials from LDS. Barriers are wave-uniform.
__global__ __launch_bounds__(768) void attn_mega_kernel(
        const float* __restrict__ Qc_g, const float* __restrict__ Kc_g, const float* __restrict__ Vc_g,
        const float* __restrict__ Qs_g, const float* __restrict__ Ks_g, const float* __restrict__ Vs_g,
        const float* __restrict__ Qt_g, const float* __restrict__ Kt_g, const float* __restrict__ Vt_g,
        short* __restrict__ Oc, short* __restrict__ Os, short* __restrict__ Ot,
        int docausal) {
    __shared__ __align__(16) float smem[3840 + 8 * 60 * 20];  // 13440 >= 3*TJ*SPAD
    int bx = blockIdx.x;
    int tid = threadIdx.x;

    if (bx < 240) {
        // ---- spatial (frame-major inputs); all 768 threads stage, 192 compute
        float* Qs = smem;
        float* Ks = smem + TJ * SPAD;
        float* Vs = smem + 2 * TJ * SPAD;
        int b = bx & 1, t = bx >> 1;
        int base = (t * TB + b) * TJ;
        for (int i = tid; i < TJ * 32; i += 768) {
            int rr = i >> 5, c4 = i & 31;
            ((f4*)(Qs + rr * SPAD))[c4] = ((const f4*)(Qs_g + (size_t)(base + rr) * TH))[c4];
            ((f4*)(Ks + rr * SPAD))[c4] = ((const f4*)(Ks_g + (size_t)(base + rr) * TH))[c4];
            ((f4*)(Vs + rr * SPAD))[c4] = ((const f4*)(Vs_g + (size_t)(base + rr) * TH))[c4];
        }
        __syncthreads();
        if (tid >= 192) return;          // no barriers after this point
        int qj = tid % TJ;
        int head = tid / TJ;
        int hb = head * THD;
        float qv[THD];
        #pragma unroll
        for (int u = 0; u < THD; ++u) qv[u] = Qs[qj * SPAD + hb + u];
        float sc[TJ];
        float m = -1e30f;
        #pragma unroll
        for (int k = 0; k < TJ; ++k) {
            float a = 0.f;
            #pragma unroll
            for (int u = 0; u < THD; ++u) a += qv[u] * Ks[k * SPAD + hb + u];
            sc[k] = a * 0.25f;
            m = fmaxf(m, sc[k]);
        }
        float sum = 0.f;
        #pragma unroll
        for (int k = 0; k < TJ; ++k) { sc[k] = __expf(sc[k] - m); sum += sc[k]; }
        float inv = 1.0f / sum;
        float o[THD];
        #pragma unroll
        for (int u = 0; u < THD; ++u) o[u] = 0.f;
        #pragma unroll
        for (int k = 0; k < TJ; ++k) {
            #pragma unroll
            for (int u = 0; u < THD; ++u) o[u] += sc[k] * Vs[k * SPAD + hb + u];
        }
        size_t off = (size_t)(base + qj) * TH + hb;
        #pragma unroll
        for (int u = 0; u < THD; ++u) Os[off + u] = f2bf(o[u] * inv);
        return;
    }

    // ---- temporal: block = (b,j,head), 12 waves, 30-key chunks ----
    int cx = bx - 240;                    // 0..383
    int head = cx & 7;
    int j = (cx >> 3) % TJ;
    int b = (cx >> 3) / TJ;
    size_t base = (size_t)((b * TJ + j) * TNH + head) * HSEG;
    float* Kb = smem;                     // 120*16 = 1920 floats
    float* Vb = smem + 1920;              // 1920 floats
    float* pbuf = smem + 3840;            // 8 slots * 60 lanes * 20 floats
    for (int i = tid; i < 480; i += 768) {
        ((f4*)Kb)[i] = ((const f4*)(Kc_g + base))[i];
        ((f4*)Vb)[i] = ((const f4*)(Vc_g + base))[i];
    }
    __syncthreads();
    int wave = tid >> 6, lane = tid & 63;
    // tasks: 0=C-lo(w0-1), 1=C-hi(w2-5), 2=S-lo(w6-7), 3=S-hi(w8-11)
    int task, chunk;
    if (wave < 2)      { task = 0; chunk = wave; }
    else if (wave < 6) { task = 1; chunk = wave - 2; }
    else if (wave < 8) { task = 2; chunk = wave - 6; }
    else               { task = 3; chunk = wave - 8; }
    int nchunks = (task & 1) ? 4 : 2;
    int iscausal = (task < 2);
    int active = (docausal || !iscausal);
    int qhi = (task & 1);
    int act = (lane < 60);
    int q = (qhi ? 60 : 0) + (act ? lane : 59);
    int k0 = chunk * 30;
    int iswriter = (chunk == nchunks - 1);
    int hasdiag = (!iscausal) && iswriter;
    int slotbase = (task == 0) ? 0 : ((task == 1) ? 1 : ((task == 2) ? 4 : 5));
    f4 a0 = {0,0,0,0}, a1 = {0,0,0,0}, a2 = {0,0,0,0}, a3 = {0,0,0,0};
    float sum = 0.f;
    if (active) {
        const float* Qg = iscausal ? Qc_g : Qt_g;
        f4 Qr0 = *(const f4*)(Qg + base + (size_t)q * THD);
        f4 Qr1 = *(const f4*)(Qg + base + (size_t)q * THD + 4);
        f4 Qr2 = *(const f4*)(Qg + base + (size_t)q * THD + 8);
        f4 Qr3 = *(const f4*)(Qg + base + (size_t)q * THD + 12);
        int qc = iscausal ? q : (q - 1);  // last valid baseline key
        #pragma unroll 5
        for (int k = k0; k < k0 + 30; ++k) {
            const float* kr = Kb + k * 16;
            f4 d = Qr0 * ((const f4*)kr)[0] + Qr1 * ((const f4*)kr)[1]
                 + Qr2 * ((const f4*)kr)[2] + Qr3 * ((const f4*)kr)[3];
            float s = (d[0] + d[1] + d[2] + d[3]) * 0.25f;
            float p = (k <= qc) ? __expf(s) : 0.f;
            sum += p;
            const float* vr = Vb + k * 16;
            a0 += p * ((const f4*)vr)[0];
            a1 += p * ((const f4*)vr)[1];
            a2 += p * ((const f4*)vr)[2];
            a3 += p * ((const f4*)vr)[3];
        }
        if (hasdiag) {                    // diagonal from lane-private special K/V
            f4 Ks0 = *(const f4*)(Kt_g + base + (size_t)q * THD);
            f4 Ks1 = *(const f4*)(Kt_g + base + (size_t)q * THD + 4);
            f4 Ks2 = *(const f4*)(Kt_g + base + (size_t)q * THD + 8);
            f4 Ks3 = *(const f4*)(Kt_g + base + (size_t)q * THD + 12);
            f4 Vd0 = *(const f4*)(Vt_g + base + (size_t)q * THD);
            f4 Vd1 = *(const f4*)(Vt_g + base + (size_t)q * THD + 4);
            f4 Vd2 = *(const f4*)(Vt_g + base + (size_t)q * THD + 8);
            f4 Vd3 = *(const f4*)(Vt_g + base + (size_t)q * THD + 12);
            f4 d = Qr0 * Ks0 + Qr1 * Ks1 + Qr2 * Ks2 + Qr3 * Ks3;
            float p = __expf((d[0] + d[1] + d[2] + d[3]) * 0.25f);
            sum += p;
            a0 += p * Vd0; a1 += p * Vd1; a2 += p * Vd2; a3 += p * Vd3;
        }
    }
    if (active && act && !iswriter) {
        float* p = pbuf + ((size_t)(slotbase + chunk) * 60 + lane) * 20;
        *(f4*)(p) = a0; *(f4*)(p + 4) = a1; *(f4*)(p + 8) = a2; *(f4*)(p + 12) = a3;
        p[16] = sum;
    }
    __syncthreads();                      // uniform: all 12 waves arrive
    if (active && act && iswriter) {
        #pragma unroll
        for (int c = 0; c < 3; ++c) {
            if (c < nchunks - 1) {        // merge partner partials
                const float* p = pbuf + ((size_t)(slotbase + c) * 60 + lane) * 20;
                a0 += *(const f4*)(p); a1 += *(const f4*)(p + 4);
                a2 += *(const f4*)(p + 8); a3 += *(const f4*)(p + 12);
                sum += p[16];
            }
        }
        float inv = 1.0f / sum;
        short* O = iscausal ? Oc : Ot;
        size_t off = (size_t)((q * TB + b) * TJ + j) * TH + head * THD;
        s4 o0 = { f2bf(a0[0]*inv), f2bf(a0[1]*inv), f2bf(a0[2]*inv), f2bf(a0[3]*inv) };
        s4 o1 = { f2bf(a1[0]*inv), f2bf(a1[1]*inv), f2bf(a1[2]*inv), f2bf(a1[3]*inv) };
        s4 o2 = { f2bf(a2[0]*inv), f2bf(a2[1]*inv), f2bf(a2[2]*inv), f2bf(a2[3]*inv) };
        s4 o3 = { f2bf(a3[0]*inv), f2bf(a3[1]*inv), f2bf(a3[2]*inv), f2bf(a3[3]*inv) };
        *(s4*)(O + off)      = o0;
        *(s4*)(O + off + 4)  = o1;
        *(s4*)(O + off + 8)  = o2;
        *(s4*)(O + off + 12) = o3;
    }
}

// ---------------- OLN compute core ----------------
__device__ __forceinline__ void oln_compute(
        const short* __restrict__ Abf, const short* __restrict__ Wbf,
        const float* __restrict__ bias, const float* __restrict__ resid,
        const float* __restrict__ g, const float* __restrict__ bln,
        int perJoint, int m0, int j,
        short* As, short* Bs, float* rsum, float* rsq, float* lnm, float* lnr,
        float o0[4], float o1[4]) {
    int tid = threadIdx.x;
    { int r = tid >> 4, s = (tid & 15) * 8;
      *(bf8*)&As[r * LDT + s] = *(const bf8*)(Abf + (size_t)(m0 + r) * TEMB + j * TH + s); }
    { int r = tid >> 1, s = (tid & 1) * 64;
      const short* p = Wbf + (perJoint ? (size_t)j * TH * TH : 0) + (size_t)r * TH + s;
      short* d = &Bs[r * LDT + s];
      #pragma unroll
      for (int cc = 0; cc < 64; cc += 8) *(bf8*)(d + cc) = *(const bf8*)(p + cc); }
    __syncthreads();
    int wave = tid >> 6, lane = tid & 63, lrow = lane & 15, lk = (lane >> 4) * 8, gr = (lane >> 4) * 4;
    f4 acc[2] = {{0,0,0,0},{0,0,0,0}};
    #pragma unroll
    for (int ks = 0; ks < 4; ++ks) {
        bf8 a  = *(const bf8*)&As[lrow * LDT + ks*32 + lk];
        bf8 b0 = *(const bf8*)&Bs[(wave*32      + lrow) * LDT + ks*32 + lk];
        bf8 b1 = *(const bf8*)&Bs[(wave*32 + 16 + lrow) * LDT + ks*32 + lk];
        acc[0] = __builtin_amdgcn_mfma_f32_16x16x32_bf16(a, b0, acc[0], 0, 0, 0);
        acc[1] = __builtin_amdgcn_mfma_f32_16x16x32_bf16(a, b1, acc[1], 0, 0, 0);
    }
    int col0 = wave*32 + lrow, col1 = col0 + 16;
    int bofs = perJoint ? j * TH : 0;
    float bv0 = bias[bofs + col0], bv1 = bias[bofs + col1];
    float v0[4], v1[4], sr_[4], sq_[4];
    #pragma unroll
    for (int rg = 0; rg < 4; ++rg) {
        size_t ro = (size_t)(m0 + gr + rg) * TEMB + j * TH;
        v0[rg] = acc[0][rg] + bv0 + resid[ro + col0];
        v1[rg] = acc[1][rg] + bv1 + resid[ro + col1];
        sr_[rg] = v0[rg] + v1[rg];
        sq_[rg] = v0[rg]*v0[rg] + v1[rg]*v1[rg];
    }
    #pragma unroll
    for (int o = 1; o < 16; o <<= 1) {
        #pragma unroll
        for (int rg = 0; rg < 4; ++rg) { sr_[rg] += __shfl_xor(sr_[rg], o); sq_[rg] += __shfl_xor(sq_[rg], o); }
    }
    if (lrow == 0) {
        #pragma unroll
        for (int rg = 0; rg < 4; ++rg) { rsum[wave*16 + gr + rg] = sr_[rg]; rsq[wave*16 + gr + rg] = sq_[rg]; }
    }
    __syncthreads();
    if (tid < 16) {
        float s = rsum[tid] + rsum[16 + tid] + rsum[32 + tid] + rsum[48 + tid];
        float q = rsq[tid] + rsq[16 + tid] + rsq[32 + tid] + rsq[48 + tid];
        float mean = s * (1.0f / TH);
        float var = q * (1.0f / TH) - mean * mean;
        lnm[tid] = mean; lnr[tid] = rsqrtf(var + 1e-5f);
    }
    __syncthreads();
    float g0 = g[col0], g1 = g[col1], l0 = bln[col0], l1 = bln[col1];
    #pragma unroll
    for (int rg = 0; rg < 4; ++rg) {
        int row = gr + rg;
        float mean = lnm[row], rs = lnr[row];
        o0[rg] = (v0[rg] - mean) * rs * g0 + l0;
        o1[rg] = (v1[rg] - mean) * rs * g1 + l1;
    }
}

// fused OLN: part2-temporal (np2 blocks) + part3 spatial+temporal (360 blocks)
__global__ __launch_bounds__(256) void mfma_olnfused_kernel(
        const short* __restrict__ A2, const short* __restrict__ Wt,
        const float* __restrict__ bt, const float* __restrict__ res2,
        const float* __restrict__ tg, const float* __restrict__ tl,
        short* __restrict__ Yb2,
        const short* __restrict__ A3s, const short* __restrict__ Ws,
        const float* __restrict__ bs, const short* __restrict__ A3t,
        const float* __restrict__ res3,
        const float* __restrict__ sg, const float* __restrict__ sl,
        short* __restrict__ Yb3, int np2) {
    __shared__ short As[16 * LDT];
    __shared__ short Bs[128 * LDT];
    __shared__ float rsum[64], rsq[64], lnm[16], lnr[16];
    int bx = blockIdx.x;
    int tid = threadIdx.x;
    int wave = tid >> 6, lane = tid & 63, lrow = lane & 15, gr = (lane >> 4) * 4;
    int col0 = wave*32 + lrow, col1 = col0 + 16;
    if (bx < np2) {
        int m0 = (bx % 15) * 16, j = bx / 15;
        float o0[4], o1[4];
        oln_compute(A2, Wt, bt, res2, tg, tl, 1, m0, j,
                    As, Bs, rsum, rsq, lnm, lnr, o0, o1);
        #pragma unroll
        for (int rg = 0; rg < 4; ++rg) {
            size_t ro = (size_t)(m0 + gr + rg) * TEMB + j * TH;
            Yb2[ro + col0] = f2bf(o0[rg]);
            Yb2[ro + col1] = f2bf(o1[rg]);
        }
    } else {
        int idx = bx - np2;
        int m0 = (idx % 15) * 16, j = idx / 15;
        float s0[4], s1[4], t0[4], t1[4];
        oln_compute(A3s, Ws, bs, res3, sg, sl, 0, m0, j,
                    As, Bs, rsum, rsq, lnm, lnr, s0, s1);
        __syncthreads();
        oln_compute(A3t, Wt, bt, res3, tg, tl, 1, m0, j,
                    As, Bs, rsum, rsq, lnm, lnr, t0, t1);
        #pragma unroll
        for (int rg = 0; rg < 4; ++rg) {
            size_t ro = (size_t)(m0 + gr + rg) * TEMB + j * TH;
            Yb3[ro + col0] = f2bf(t0[rg] + s0[rg]);
            Yb3[ro + col1] = f2bf(t1[rg] + s1[rg]);
        }
    }
}

// ---------------- FFN MFMA GEMMs ----------------
__global__ __launch_bounds__(256) void mfma_ffn1_kernel(
        const short* __restrict__ Ybf, const short* __restrict__ W1bf,
        const float* __restrict__ b1, short* __restrict__ Fb) {
    __shared__ short As[64 * LDT], Bs[64 * LDT];
    int tid = threadIdx.x;
    int m0 = blockIdx.x * 64, n0 = blockIdx.y * 64;
    stage_bf(As, Ybf + (size_t)m0 * TH, TH, 64, tid);
    stage_bf(Bs, W1bf + (size_t)n0 * TH, TH, 64, tid);
    __syncthreads();
    int wave = tid >> 6, lane = tid & 63;
    f4 acc[2][2] = {{{0,0,0,0},{0,0,0,0}},{{0,0,0,0},{0,0,0,0}}};
    mfma_tile64(As, Bs, wave, lane, acc);
    int wm = wave >> 1, wn = wave & 1, lrow = lane & 15, gr = (lane >> 4) * 4;
    #pragma unroll
    for (int ni = 0; ni < 2; ++ni) {
        int col = n0 + wn*32 + ni*16 + lrow;
        float bv = b1[col];
        #pragma unroll
        for (int mi = 0; mi < 2; ++mi)
            #pragma unroll
            for (int rg = 0; rg < 4; ++rg) {
                int tr = wm*32 + mi*16 + gr + rg;
                float v = 2.0f * fmaxf(acc[mi][ni][rg] + bv, 0.0f);
                Fb[(size_t)(m0 + tr) * TF + col] = f2bf(v);
            }
    }
}

// rows < splitrow -> OutA (f32+bf16); rows >= splitrow -> OutB[row-splitrow]
__global__ __launch_bounds__(256) void mfma_ffn2_kernel(
        const short* __restrict__ Fb, const short* __restrict__ W2bf,
        const float* __restrict__ b2, float* __restrict__ OutAf,
        short* __restrict__ OutAbf, float* __restrict__ OutBf,
        short* __restrict__ OutBbf, int splitrow) {
    __shared__ short As[64 * LDT], Bs[64 * LDT];
    int tid = threadIdx.x;
    int m0 = blockIdx.x * 64, n0 = blockIdx.y * 64;
    int wave = tid >> 6, lane = tid & 63;
    f4 acc[2][2] = {{{0,0,0,0},{0,0,0,0}},{{0,0,0,0},{0,0,0,0}}};
    #pragma unroll
    for (int kk = 0; kk < 2; ++kk) {
        stage_bf(As, Fb + (size_t)m0 * TF + kk * 128, TF, 64, tid);
        stage_bf(Bs, W2bf + (size_t)n0 * TF + kk * 128, TF, 64, tid);
        __syncthreads();
        mfma_tile64(As, Bs, wave, lane, acc);
        __syncthreads();
    }
    int wm = wave >> 1, wn = wave & 1, lrow = lane & 15, gr = (lane >> 4) * 4;
    #pragma unroll
    for (int ni = 0; ni < 2; ++ni) {
        int col = n0 + wn*32 + ni*16 + lrow;
        float bv = b2[col];
        #pragma unroll
        for (int mi = 0; mi < 2; ++mi)
            #pragma unroll
            for (int rg = 0; rg < 4; ++rg) {
                int tr = wm*32 + mi*16 + gr + rg;
                int row = m0 + tr;
                float v = acc[mi][ni][rg] + bv;
                if (row < splitrow) {
                    size_t off = (size_t)row * TH + col;
                    OutAf[off] = v; OutAbf[off] = f2bf(v);
                } else {
                    size_t off = (size_t)(row - splitrow) * TH + col;
                    OutBf[off] = v; OutBbf[off] = f2bf(v);
                }
            }
    }
}

// ---------------- final projection + residual ----------------
__global__ void final_kernel(const float* __restrict__ r4, const float* __restrict__ Wout,
                             const float* __restrict__ bout, const float* __restrict__ src,
                             const float* __restrict__ tgt, float* __restrict__ out) {
    int idx = blockIdx.x * 256 + threadIdx.x;
    if (idx >= TB * TW * TD) return;
    int d = idx % TD;
    int t = (idx / TD) % TW;
    int b = idx / (TD * TW);
    int j = d / 9, o = d % 9;
    const float* rr = r4 + (size_t)((t * TB + b) * TJ + j) * TH;
    const float* wt = Wout + (size_t)o * TH;
    float acc = bout[o];
    #pragma unroll 4
    for (int h = 0; h < TH; ++h) acc += rr[h] * wt[h];
    float cv = (t < 60) ? src[((size_t)b * 60 + t) * TD + d]
                        : tgt[((size_t)b * 61 + (t - 60)) * TD + d];
    out[idx] = acc + cv;
}

extern "C" void kernel_launch(void* const* d_in, const int* in_sizes, int n_in,
                              void* d_out, int out_size, void* d_ws, size_t ws_size,
                              hipStream_t stream) {
    const float* src    = (const float*)d_in[0];
    const float* tgt    = (const float*)d_in[1];
    const float* Wemb   = (const float*)d_in[2];
    const float* bemb   = (const float*)d_in[3];
    const float* Wqkv_s = (const float*)d_in[4];
    const float* bqkv_s = (const float*)d_in[5];
    const float* Wo_s   = (const float*)d_in[6];
    const float* bo_s   = (const float*)d_in[7];
    const float* sn_g   = (const float*)d_in[8];
    const float* sn_b   = (const float*)d_in[9];
    const float* Wqkv_t = (const float*)d_in[10];
    const float* bqkv_t = (const float*)d_in[11];
    const float* Wo_t   = (const float*)d_in[12];
    const float* bo_t   = (const float*)d_in[13];
    const float* tn_g   = (const float*)d_in[14];
    const float* tn_b   = (const float*)d_in[15];
    const float* W1     = (const float*)d_in[16];
    const float* b1     = (const float*)d_in[17];
    const float* W2     = (const float*)d_in[18];
    const float* b2     = (const float*)d_in[19];
    const float* Wout   = (const float*)d_in[20];
    const float* bout   = (const float*)d_in[21];
    float* out = (float*)d_out;

    const size_t RH = (size_t)TROWS * TH;   // 737280
    float* f = (float*)d_ws;
    float* x0    = f;
    float* Kbase = x0 + RH;              // 4*RH (head-major per layer)
    float* Vbase = Kbase + 4 * RH;       // 4*RH
    float* r     = Vbase + 4 * RH;
    float* Qp2   = r + RH;
    float* Qs    = Qp2 + RH;
    float* Ks    = Qs + RH;
    float* Vs    = Ks + RH;
    float* Qt    = Vs + RH;
    float* Kt    = Qt + RH;
    float* Vt    = Kt + RH;
    float* Bb0   = Vt + RH;
    float* Bb1   = Bb0 + RH;
    short* sbase   = (short*)(Bb1 + RH);
    short* x0bf    = sbase;
    short* rbf     = x0bf + RH;
    short* attnb_c = rbf + RH;
    short* attnb_s = attnb_c + RH;
    short* attnb_t = attnb_s + RH;
    short* yball   = attnb_t + RH;       // 2*RH (part2 lower, part3 upper)
    short* fball   = yball + 2 * RH;     // 2*TROWS*TF
    short* Bb0bf   = fball + 2 * (size_t)TROWS * TF;
    short* Bb1bf   = Bb0bf + RH;
    short* wbf     = Bb1bf + RH;         // NW_TOT shorts
    short* wembbf  = wbf + NW_TOT;       // TEMB*KPAD shorts
    short* cbufbf  = wembbf + (size_t)TEMB * KPAD;  // TBF*KPAD shorts

    const short* wqkvs_bf = wbf;
    const short* wos_bf   = wbf + OFF_O_S;
    const short* wqkvt_bf = wbf + OFF_QKV_T;
    const short* wot_bf   = wbf + OFF_O_T;
    const short* w1bf     = wbf + OFF_W1;
    const short* w2bf     = wbf + OFF_W2;

    // 0. weights -> bf16 (incl. padded Wemb) + gather concat -> padded bf16
    convgather_kernel<<<NB_CONV + NB_WEMB + NB_CBUF, 256, 0, stream>>>(
        Wqkv_s, Wo_s, Wqkv_t, Wo_t, W1, W2, wbf,
        Wemb, wembbf, src, tgt, cbufbf);

    // 1. embedding MFMA GEMM (+bias+PE); writes x0/x0bf and r/rbf
    mfma_embed_kernel<<<dim3(4, 48), 256, 0, stream>>>(
        cbufbf, wembbf, bemb, x0, x0bf, r, rbf);

    // 2+3. per-layer mega launches
    const float* Binf = x0;
    const short* Binbf = x0bf;
    for (int l = 0; l < 4; ++l) {
        int p2n = (l < 3) ? 6 : 4;
        int n0base = (l < 3) ? 0 : 128;
        int np2 = (l < 3) ? 360 : 0;
        const short* wt_l = wqkvt_bf + (size_t)l * TJ * 3 * TH * TH;
        const short* ws_l = wqkvs_bf + (size_t)l * 3 * TH * TH;
        const float* bt_l = bqkv_t + (size_t)l * TJ * 3 * TH;
        const float* bs_l = bqkv_s + (size_t)l * 3 * TH;

        mfma_qkvmega_kernel<<<dim3(4, p2n + 12, 24), 256, 0, stream>>>(
            Binbf, rbf, wt_l, ws_l, bt_l, bs_l,
            Qp2, Kbase + l * RH, Vbase + l * RH,
            Qs, Ks, Vs, Qt, Kt, Vt, p2n, n0base);

        attn_mega_kernel<<<240 + 384, 768, 0, stream>>>(
            Qp2, Kbase + l * RH, Vbase + l * RH,
            Qs, Ks, Vs, Qt, Kt, Vt,
            attnb_c, attnb_s, attnb_t, (l < 3) ? 1 : 0);

        mfma_olnfused_kernel<<<np2 + 360, 256, 0, stream>>>(
            attnb_c, wot_bf + (size_t)l * TJ * TH * TH, bo_t + (size_t)l * TJ * TH,
            Binf, tn_g + l * TH, tn_b + l * TH, yball,
            attnb_s, wos_bf + (size_t)l * TH * TH, bo_s + (size_t)l * TH,
            attnb_t, r, sn_g + l * TH, sn_b + l * TH, yball + RH, np2);

        if (l < 3) {
            mfma_ffn1_kernel<<<dim3(180, 4), 256, 0, stream>>>(
                yball, w1bf + (size_t)l * TF * TH, b1 + l * TF, fball);
            float* Boutf = (l & 1) ? Bb1 : Bb0;
            short* Boutbf = (l & 1) ? Bb1bf : Bb0bf;
            mfma_ffn2_kernel<<<dim3(180, 2), 256, 0, stream>>>(
                fball, w2bf + (size_t)l * TH * TF, b2 + l * TH,
                Boutf, Boutbf, r, rbf, TROWS);
            Binf = Boutf; Binbf = Boutbf;
        } else {
            mfma_ffn1_kernel<<<dim3(90, 4), 256, 0, stream>>>(
                yball + RH, w1bf + (size_t)l * TF * TH, b1 + l * TF, fball);
            mfma_ffn2_kernel<<<dim3(90, 2), 256, 0, stream>>>(
                fball, w2bf + (size_t)l * TH * TF, b2 + l * TH,
                r, rbf, r, rbf, 0);
        }
    }

    // 4. output projection + residual
    final_kernel<<<(TB * TW * TD + 255) / 256, 256, 0, stream>>>(r, Wout, bout, src, tgt, out);
}